// Round 10
// baseline (470.682 us; speedup 1.0000x reference)
//
#include <hip/hip_runtime.h>

// ---------------------------------------------------------------------------
// Part_Graph: deformable-conv message passing over a 6-node part graph.
// B=2, H=W=96, IN=256, HID=10, P=6, E=12, K=9 taps.  ALL I/O is float32.
// dcn: 512-thread tap-split (half A: conv t0-3 / samp k0-4; half B: rest),
// partial om/acc exchanged via LDS. mgq: 4-batched loads for MLP.
// ---------------------------------------------------------------------------

#define NE 12
#define NPART 6
#define BB 2
#define HH 96
#define WW 96
#define HWD (HH*WW)          // 9216
#define CIN2 20              // 2*HID concat channels
#define NHID 10
#define NIN 256

// LDS tile geometry: 16x16 output tile, +-2 halo -> 20x20 box.
#define BOX 20
#define BCOL 21              // padded col stride (bank stagger)
#define PLANE (BOX*BCOL*4)   // floats per 4-channel plane = 1680

__device__ __forceinline__ float sigf(float x) { return 1.f / (1.f + __expf(-x)); }

// ---------------------------------------------------------------------------
// Weight transposition to hot-loop friendly layouts (fp32 -> fp32):
//   off*_wt : [e][t=9][c=20][o=27]   (conv: per tap, n[c] dot into om[o])
//   dcn*_wt : [e][k=9][c=20][o]      (sampling: per (k,c) matvec over o)
//   upd_wt  : [p][c=256][o=10]
// ---------------------------------------------------------------------------
__global__ __launch_bounds__(256)
void xpose_weights(const float* __restrict__ off1_w, const float* __restrict__ off1_b,
                   const float* __restrict__ dcn1_w,
                   const float* __restrict__ off2_w, const float* __restrict__ off2_b,
                   const float* __restrict__ dcn2_w,
                   const float* __restrict__ upd_w,
                   float* __restrict__ o1wt, float* __restrict__ o1b, float* __restrict__ d1wt,
                   float* __restrict__ o2wt, float* __restrict__ o2b, float* __restrict__ d2wt,
                   float* __restrict__ uwt)
{
    int idx = blockIdx.x * 256 + threadIdx.x;
    if (idx < 58320) {                       // off1_wt [e][t][c][27]
        int e = idx / 4860, r = idx % 4860;
        int t = r / 540, r2 = r % 540, c = r2 / 27, o = r2 % 27;
        o1wt[idx] = off1_w[((e*27 + o)*CIN2 + c)*9 + t];
        return;
    }
    idx -= 58320;
    if (idx < 324) { o1b[idx] = off1_b[idx]; return; }
    idx -= 324;
    if (idx < 43200) {                       // dcn1_wt [e][k][c][20]
        int e = idx / 3600, r = idx % 3600;
        int k = r / 400, r2 = r % 400, c = r2 / 20, o = r2 % 20;
        d1wt[idx] = dcn1_w[((e*20 + o)*20 + c)*9 + k];
        return;
    }
    idx -= 43200;
    if (idx < 58320) {                       // off2_wt [e][t][c][27]
        int e = idx / 4860, r = idx % 4860;
        int t = r / 540, r2 = r % 540, c = r2 / 27, o = r2 % 27;
        o2wt[idx] = off2_w[((e*27 + o)*CIN2 + c)*9 + t];
        return;
    }
    idx -= 58320;
    if (idx < 324) { o2b[idx] = off2_b[idx]; return; }
    idx -= 324;
    if (idx < 21600) {                       // dcn2_wt [e][k][c][10]
        int e = idx / 1800, r = idx % 1800;
        int k = r / 200, r2 = r % 200, c = r2 / 10, o = r2 % 10;
        d2wt[idx] = dcn2_w[((e*10 + o)*20 + c)*9 + k];
        return;
    }
    idx -= 21600;
    if (idx < 15360) {                       // upd_wt [p][c][10]
        int p = idx / 2560, r = idx % 2560, c = r / 10, o = r % 10;
        uwt[idx] = upd_w[(p*10 + o)*256 + c];
        return;
    }
}

// ---------------------------------------------------------------------------
// Sampling tap body (k MUST expand to a literal so om[] stays reg-indexed).
// ---------------------------------------------------------------------------
#define SAMPLE_TAP(k)                                                          \
{                                                                              \
    float m  = sigf(om[18 + (k)]);                                             \
    float ys = (float)(h + (k)/3 - 1) + om[2*(k)];                             \
    float xs = (float)(w + (k)%3 - 1) + om[2*(k) + 1];                         \
    float y0f = floorf(ys), x0f = floorf(xs);                                  \
    int iy = (int)y0f, ix = (int)x0f;                                          \
    float fy = ys - y0f, fx = xs - x0f;                                        \
    bool vy0 = (iy >= 0) && (iy < HH);                                         \
    bool vy1 = (iy >= -1) && (iy < HH-1);                                      \
    bool vx0 = (ix >= 0) && (ix < WW);                                         \
    bool vx1 = (ix >= -1) && (ix < WW-1);                                      \
    float w00 = (vy0 && vx0) ? (1.f-fy)*(1.f-fx)*m : 0.f;                      \
    float w01 = (vy0 && vx1) ? (1.f-fy)*fx*m       : 0.f;                      \
    float w10 = (vy1 && vx0) ? fy*(1.f-fx)*m       : 0.f;                      \
    float w11 = (vy1 && vx1) ? fy*fx*m             : 0.f;                      \
    int cy0 = min(max(iy,   0), HH-1), cy1 = min(max(iy+1, 0), HH-1);          \
    int cx0 = min(max(ix,   0), WW-1), cx1 = min(max(ix+1, 0), WW-1);          \
    const float* wk = wd + (k)*CIN2*COUT;                                      \
    bool staged = (cy0 >= r0) && (cy1 <= r0 + BOX-1) &&                        \
                  (cx0 >= c0) && (cx1 <= c0 + BOX-1);                          \
    if (staged) {                                                              \
        const int p00 = ((cy0-r0)*BCOL + (cx0-c0))*4;                          \
        const int p01 = ((cy0-r0)*BCOL + (cx1-c0))*4;                          \
        const int p10 = ((cy1-r0)*BCOL + (cx0-c0))*4;                          \
        const int p11 = ((cy1-r0)*BCOL + (cx1-c0))*4;                          \
        float4 a  = *reinterpret_cast<const float4*>(lds + p00);               \
        float4 bq = *reinterpret_cast<const float4*>(lds + p01);               \
        float4 cq = *reinterpret_cast<const float4*>(lds + p10);               \
        float4 dq = *reinterpret_cast<const float4*>(lds + p11);               \
        _Pragma("unroll 1")                                                    \
        for (int c4 = 0; c4 < 5; c4++) {                                       \
            float4 a2 = make_float4(0.f,0.f,0.f,0.f);                          \
            float4 b2 = a2, c2 = a2, d2 = a2;                                  \
            if (c4 < 4) {                                                      \
                const float* pl = lds + (c4+1)*PLANE;                          \
                a2 = *reinterpret_cast<const float4*>(pl + p00);               \
                b2 = *reinterpret_cast<const float4*>(pl + p01);               \
                c2 = *reinterpret_cast<const float4*>(pl + p10);               \
                d2 = *reinterpret_cast<const float4*>(pl + p11);               \
            }                                                                  \
            const float* wc = wk + c4*4*COUT;                                  \
            _Pragma("unroll")                                                  \
            for (int j = 0; j < 4; j++) {                                      \
                float s = w00*(&a.x)[j] + w01*(&bq.x)[j]                       \
                        + w10*(&cq.x)[j] + w11*(&dq.x)[j];                     \
                _Pragma("unroll")                                              \
                for (int o = 0; o < COUT; o++)                                 \
                    acc[o] = fmaf(s, wc[j*COUT + o], acc[o]);                  \
            }                                                                  \
            a = a2; bq = b2; cq = c2; dq = d2;                                 \
        }                                                                      \
    } else {                                                                   \
        int o00 = cy0*WW + cx0, o01 = cy0*WW + cx1;                            \
        int o10 = cy1*WW + cx0, o11 = cy1*WW + cx1;                            \
        _Pragma("unroll 1")                                                    \
        for (int c = 0; c < CIN2; c++) {                                       \
            const float* src;                                                  \
            float sc = 1.f, sh = 0.f;                                          \
            if (L1) {                                                          \
                int part = (c < NHID) ? esrc[e] : edst[e];                     \
                int ch   = (c < NHID) ? c : c - NHID;                          \
                src = xp + ((size_t)(part*BB + b)*NHID + ch)*HWD;              \
            } else {                                                           \
                src = xin + (size_t)c*HWD;                                     \
                sc = bnS[e*CIN2 + c]; sh = bnT[e*CIN2 + c];                    \
            }                                                                  \
            float av = src[o00], bv = src[o01], cv = src[o10], dv = src[o11];  \
            if (!L1) {                                                         \
                av = fmaxf(fmaf(av, sc, sh), 0.f);                             \
                bv = fmaxf(fmaf(bv, sc, sh), 0.f);                             \
                cv = fmaxf(fmaf(cv, sc, sh), 0.f);                             \
                dv = fmaxf(fmaf(dv, sc, sh), 0.f);                             \
            }                                                                  \
            float s = w00*av + w01*bv + w10*cv + w11*dv;                       \
            const float* wc = wk + c*COUT;                                     \
            _Pragma("unroll")                                                  \
            for (int o = 0; o < COUT; o++) acc[o] = fmaf(s, wc[o], acc[o]);    \
        }                                                                      \
    }                                                                          \
}

// ---------------------------------------------------------------------------
// Fused, LDS-tiled DCNv2 layer — 512-thread tap-split.
//   half A (tid<256): conv taps 0-3 (+bias), sampling taps 0-4
//   half B          : conv taps 4-8,         sampling taps 5-8
// Partial om exchanged via LDS (slice-disjoint), partial acc reduced in LDS.
// grid: (36, B, E); 61.2 KB LDS -> 2 blocks/CU = 4 waves/SIMD sustained.
// ---------------------------------------------------------------------------
template<int COUT, bool L1>
__global__ __launch_bounds__(512, 4)
void dcn_tiled(const float* __restrict__ xin_all,
               const float* __restrict__ xp,      // only for L1 gather
               const int* __restrict__ esrc, const int* __restrict__ edst,
               const float* __restrict__ wo_all,  // [E][9][20][27]
               const float* __restrict__ bo_all,  // [E][27]
               const float* __restrict__ wd_all,  // [E][9][20][COUT]
               const float* __restrict__ bnS, const float* __restrict__ bnT,
               float* __restrict__ out)
{
    const int b = blockIdx.y, e = blockIdx.z;
    const int ty0 = (blockIdx.x / 6) * 16, tx0 = (blockIdx.x % 6) * 16;
    const int tid = threadIdx.x;
    const int half = tid >> 8;
    const int stid = tid & 255;
    const int ly = stid >> 4, lx = stid & 15;
    const int h = ty0 + ly, w = tx0 + lx;
    const int r0 = ty0 - 2, c0 = tx0 - 2;          // staged box origin

    const float* __restrict__ xin = xin_all + (size_t)(e*BB + b)*CIN2*HWD;
    const float* __restrict__ wo  = wo_all + (size_t)e*9*CIN2*27;
    const float* __restrict__ bo  = bo_all + e*27;
    const float* __restrict__ wd  = wd_all + (size_t)e*9*CIN2*COUT;

    __shared__ float lds[5*PLANE];                 // 33.6 KB input tile
    __shared__ float red[27*256];                  // 27.6 KB om/acc exchange

    // ---- stage: 2000 float4 quads = 20ch x 20rows x 5 (all 512 threads) ----
    #pragma unroll 1
    for (int i = tid; i < 2000; i += 512) {
        int c   = i / 100;
        int rem = i - c*100;
        int rr  = rem / 5;
        int q   = rem - rr*5;
        const float* src;
        float sc = 1.f, sh = 0.f;
        if (L1) {
            int part = (c < NHID) ? esrc[e] : edst[e];
            int ch   = (c < NHID) ? c : c - NHID;
            src = xp + ((size_t)(part*BB + b)*NHID + ch)*HWD;
        } else {
            src = xin + (size_t)c*HWD;
            sc = bnS[e*CIN2 + c]; sh = bnT[e*CIN2 + c];
        }
        int y = r0 + rr, xb = c0 + 4*q;
        float4 v = make_float4(0.f, 0.f, 0.f, 0.f);
        if (y >= 0 && y < HH) {
            const float* row = src + y*WW;
            if (xb >= 0 && xb + 3 < WW) {
                v = *reinterpret_cast<const float4*>(row + xb);
            } else {
                if (xb+0 >= 0 && xb+0 < WW) v.x = row[xb+0];
                if (xb+1 >= 0 && xb+1 < WW) v.y = row[xb+1];
                if (xb+2 >= 0 && xb+2 < WW) v.z = row[xb+2];
                if (xb+3 >= 0 && xb+3 < WW) v.w = row[xb+3];
            }
            if (!L1) {      // pad stays 0 (matches zero-padding semantics)
                v.x = fmaxf(fmaf(v.x, sc, sh), 0.f);
                v.y = fmaxf(fmaf(v.y, sc, sh), 0.f);
                v.z = fmaxf(fmaf(v.z, sc, sh), 0.f);
                v.w = fmaxf(fmaf(v.w, sc, sh), 0.f);
            }
        }
        float* plane = lds + (c >> 2)*PLANE;
        int cl = c & 3;
        int base = (rr*BCOL + 4*q)*4 + cl;
        plane[base + 0]  = v.x;
        plane[base + 4]  = v.y;
        plane[base + 8]  = v.z;
        plane[base + 12] = v.w;
    }
    __syncthreads();

    // ---- offset conv (tap-split): A taps 0-3 (+bias), B taps 4-8 ----
    float om[27];
    if (half == 0) {
        #pragma unroll
        for (int o = 0; o < 27; o++) om[o] = bo[o];
    } else {
        #pragma unroll
        for (int o = 0; o < 27; o++) om[o] = 0.f;
    }

    const int tA = half ? 4 : 0, tB = half ? 9 : 4;
    #pragma unroll 1
    for (int t = tA; t < tB; t++) {
        const int rr = ly + 2 + (t/3) - 1, cc = lx + 2 + (t%3) - 1;
        const int pix = (rr*BCOL + cc)*4;
        const float* wt = wo + t*CIN2*27;
        float4 n = *reinterpret_cast<const float4*>(&lds[pix]);   // chunk 0
        #pragma unroll 1
        for (int c4 = 0; c4 < 5; c4++) {
            float4 nn = make_float4(0.f, 0.f, 0.f, 0.f);
            if (c4 < 4)
                nn = *reinterpret_cast<const float4*>(&lds[(c4+1)*PLANE + pix]);
            const float* wc = wt + c4*4*27;
            #pragma unroll
            for (int j = 0; j < 4; j++) {
                float nv = (&n.x)[j];
                #pragma unroll
                for (int o = 0; o < 27; o++) om[o] = fmaf(nv, wc[j*27 + o], om[o]);
            }
            n = nn;
        }
    }

    // ---- om exchange: sliceA = om[0..9,18..22] (A's taps), sliceB = om[10..17,23..26]
    // slots: 0..9 <- om[0..9], 10..14 <- om[18..22], 15..22 <- om[10..17], 23..26 <- om[23..26]
    if (half == 0) {            // A writes its partial of B's slice
        #pragma unroll
        for (int j = 0; j < 8; j++) red[(15+j)*256 + stid] = om[10+j];
        #pragma unroll
        for (int j = 0; j < 4; j++) red[(23+j)*256 + stid] = om[23+j];
    } else {                    // B writes its partial of A's slice
        #pragma unroll
        for (int j = 0; j < 10; j++) red[j*256 + stid] = om[j];
        #pragma unroll
        for (int j = 0; j < 5; j++) red[(10+j)*256 + stid] = om[18+j];
    }
    __syncthreads();
    if (half == 0) {            // A completes its slice
        #pragma unroll
        for (int j = 0; j < 10; j++) om[j] += red[j*256 + stid];
        #pragma unroll
        for (int j = 0; j < 5; j++) om[18+j] += red[(10+j)*256 + stid];
    } else {                    // B completes its slice
        #pragma unroll
        for (int j = 0; j < 8; j++) om[10+j] += red[(15+j)*256 + stid];
        #pragma unroll
        for (int j = 0; j < 4; j++) om[23+j] += red[(23+j)*256 + stid];
    }
    __syncthreads();            // red consumed; safe to reuse for acc

    // ---- deformable sampling (tap-split): A k=0..4, B k=5..8 ----
    float acc[COUT];
    #pragma unroll
    for (int o = 0; o < COUT; o++) acc[o] = 0.f;

    if (half == 0) {
        SAMPLE_TAP(0) SAMPLE_TAP(1) SAMPLE_TAP(2) SAMPLE_TAP(3) SAMPLE_TAP(4)
    } else {
        SAMPLE_TAP(5) SAMPLE_TAP(6) SAMPLE_TAP(7) SAMPLE_TAP(8)
    }

    // ---- acc reduction: A writes partial, B adds and stores ----
    if (half == 0) {
        #pragma unroll
        for (int o = 0; o < COUT; o++) red[o*256 + stid] = acc[o];
    }
    __syncthreads();
    if (half == 1) {
        float* op = out + ((size_t)(e*BB + b)*COUT)*HWD + h*WW + w;
        #pragma unroll
        for (int o = 0; o < COUT; o++)
            op[(size_t)o*HWD] = acc[o] + red[o*256 + stid];
    }
}

// ---------------------------------------------------------------------------
// BN statistics (training mode, biased var, eps=1e-5), folding gamma/beta:
//   scale = g*rstd, shift = beta - mean*scale
// ---------------------------------------------------------------------------
__device__ __forceinline__ void bn_finish(float s1, float s2, int n, float g, float bt,
                                          float* scale, float* shift, int idx)
{
    float mean = s1 / (float)n;
    float var  = fmaxf(s2 / (float)n - mean*mean, 0.f);
    float rs   = rsqrtf(var + 1e-5f);
    scale[idx] = g * rs;
    shift[idx] = bt - mean * g * rs;
}

// stats over flat layout [G][B][C][HWD]; one block per (g,c); grid = G*C
template<int C>
__global__ __launch_bounds__(256)
void bn_stats_flat(const float* __restrict__ x, const float* __restrict__ gamma,
                   const float* __restrict__ beta, float* __restrict__ scale,
                   float* __restrict__ shift)
{
    const int gc = blockIdx.x;
    const int g = gc / C, c = gc % C;
    const int N = BB * HWD;
    float s1 = 0.f, s2 = 0.f;
    for (int idx = threadIdx.x; idx < N; idx += 256) {
        int b = idx / HWD, p = idx % HWD;
        float v = x[((size_t)(g*BB + b)*C + c)*HWD + p];
        s1 += v; s2 += v*v;
    }
    __shared__ float r1[256], r2[256];
    r1[threadIdx.x] = s1; r2[threadIdx.x] = s2;
    __syncthreads();
    for (int s = 128; s > 0; s >>= 1) {
        if (threadIdx.x < s) { r1[threadIdx.x] += r1[threadIdx.x+s]; r2[threadIdx.x] += r2[threadIdx.x+s]; }
        __syncthreads();
    }
    if (threadIdx.x == 0)
        bn_finish(r1[0], r2[0], N, gamma[gc], beta[gc], scale, shift, gc);
}

// ---------------------------------------------------------------------------
// Fused msg + gate + q (scalar, MLP via 4-batched loads):
// grid: (36, B, P)
// ---------------------------------------------------------------------------
__global__ __launch_bounds__(256)
void mgq_kernel(const float* __restrict__ t2all, const float* __restrict__ s2,
                const float* __restrict__ sh2, const float* __restrict__ o_w,
                const float* __restrict__ o_b, const float* __restrict__ a_w,
                const float* __restrict__ a_b, const float* __restrict__ xp,
                const float* __restrict__ xh,
                const float* __restrict__ att_w, const float* __restrict__ att_b,
                const float* __restrict__ du_w, const float* __restrict__ du_b,
                const float* __restrict__ dl_w, const float* __restrict__ dl_b,
                const int* __restrict__ esrc, const int* __restrict__ edst,
                const float* __restrict__ p_fea, const float* __restrict__ wq_all,
                float* __restrict__ y)
{
    int px = blockIdx.x * 256 + threadIdx.x;
    int b = blockIdx.y, p = blockIdx.z;

    // self-attention
    float s = att_b[p];
    #pragma unroll
    for (int c = 0; c < NHID; c++)
        s += xp[((size_t)(p*BB + b)*NHID + c)*HWD + px] * att_w[p*NHID + c];
    float satt = sigf(s);

    // half-body decomposition gate
    int hs = (p < 4) ? 0 : 1;
    const float* dw = (p < 4) ? du_w : dl_w;
    float d = (p < 4) ? du_b[0] : dl_b[0];
    #pragma unroll
    for (int c = 0; c < NHID; c++)
        d += xh[((size_t)(hs*BB + b)*NHID + c)*HWD + px] * dw[c];
    float dec = sigf(d);

    // incoming-edge messages (each part has exactly 2 in-edges)
    float xpp = 0.f;
    for (int e = 0; e < NE; e++) {
        if (edst[e] != p) continue;
        float sab = o_b[e];
        #pragma unroll
        for (int c = 0; c < NHID; c++) {
            float v = t2all[((size_t)(e*BB + b)*NHID + c)*HWD + px];
            v = fmaxf(fmaf(v, s2[e*NHID+c], sh2[e*NHID+c]), 0.f);
            sab += v * o_w[e*NHID + c];
        }
        int sp = esrc[e];
        float sa = a_b[e];
        #pragma unroll
        for (int c = 0; c < NHID; c++)
            sa += xp[((size_t)(sp*BB + b)*NHID + c)*HWD + px] * a_w[e*NHID + c];
        xpp += sigf(sab) * (1.f - sigf(sa));
    }
    float gate = 1.f + dec + satt + xpp;

    // 256 -> 10 projection; 4 loads in flight per iteration (MLP)
    const float* wq = wq_all + (size_t)p*NIN*NHID;     // [c][10]
    const float* pf = p_fea + (size_t)b*NIN*HWD + px;
    float acc[NHID];
    #pragma unroll
    for (int o = 0; o < NHID; o++) acc[o] = 0.f;
    for (int c = 0; c < NIN; c += 4) {
        float v0 = pf[(size_t)(c+0)*HWD];
        float v1 = pf[(size_t)(c+1)*HWD];
        float v2 = pf[(size_t)(c+2)*HWD];
        float v3 = pf[(size_t)(c+3)*HWD];
        const float* wc = wq + c*NHID;
        #pragma unroll
        for (int o = 0; o < NHID; o++) acc[o] = fmaf(v0, wc[o], acc[o]);
        #pragma unroll
        for (int o = 0; o < NHID; o++) acc[o] = fmaf(v1, wc[NHID + o], acc[o]);
        #pragma unroll
        for (int o = 0; o < NHID; o++) acc[o] = fmaf(v2, wc[2*NHID + o], acc[o]);
        #pragma unroll
        for (int o = 0; o < NHID; o++) acc[o] = fmaf(v3, wc[3*NHID + o], acc[o]);
    }
    float* yp = y + ((size_t)(p*BB + b)*NHID)*HWD + px;
    #pragma unroll
    for (int o = 0; o < NHID; o++) yp[(size_t)o*HWD] = acc[o] * gate;
}

// ---------------------------------------------------------------------------
// out = relu(bn5(y));   grid: (36, B*HID, P)
// ---------------------------------------------------------------------------
__global__ __launch_bounds__(256)
void out_kernel(const float* __restrict__ y, const float* __restrict__ s5,
                const float* __restrict__ t5, float* __restrict__ out)
{
    int px = blockIdx.x * 256 + threadIdx.x;
    int bo = blockIdx.y, p = blockIdx.z;
    int b = bo / NHID, o = bo % NHID;
    size_t idx = ((size_t)(p*BB + b)*NHID + o)*HWD + px;
    out[idx] = fmaxf(fmaf(y[idx], s5[p*NHID+o], t5[p*NHID+o]), 0.f);
}

// ---------------------------------------------------------------------------
// launcher
// ---------------------------------------------------------------------------
extern "C" void kernel_launch(void* const* d_in, const int* in_sizes, int n_in,
                              void* d_out, int out_size, void* d_ws, size_t ws_size,
                              hipStream_t stream)
{
    (void)in_sizes; (void)n_in; (void)out_size; (void)ws_size;

    const float* p_fea  = (const float*)d_in[0];
    const float* xp     = (const float*)d_in[1];
    const float* xh     = (const float*)d_in[2];
    const float* att_w  = (const float*)d_in[3];
    const float* att_b  = (const float*)d_in[4];
    const float* du_w   = (const float*)d_in[5];
    const float* du_b   = (const float*)d_in[6];
    const float* dl_w   = (const float*)d_in[7];
    const float* dl_b   = (const float*)d_in[8];
    const float* upd_w  = (const float*)d_in[9];
    const float* upd_g  = (const float*)d_in[10];
    const float* upd_b  = (const float*)d_in[11];
    const float* off1_w = (const float*)d_in[12];
    const float* off1_b = (const float*)d_in[13];
    const float* dcn1_w = (const float*)d_in[14];
    const float* bn1_g  = (const float*)d_in[15];
    const float* bn1_b  = (const float*)d_in[16];
    const float* off2_w = (const float*)d_in[17];
    const float* off2_b = (const float*)d_in[18];
    const float* dcn2_w = (const float*)d_in[19];
    const float* bn2_g  = (const float*)d_in[20];
    const float* bn2_b  = (const float*)d_in[21];
    const float* out_w  = (const float*)d_in[22];
    const float* out_b  = (const float*)d_in[23];
    const float* aatt_w = (const float*)d_in[24];
    const float* aatt_b = (const float*)d_in[25];
    const int* esrc     = (const int*)d_in[26];
    const int* edst     = (const int*)d_in[27];
    float* outp = (float*)d_out;
    float* ws = (float*)d_ws;

    // workspace layout (float offsets)
    constexpr size_t o_x1   = 0;                                    // [E][B][20][HWD]
    constexpr size_t o_t2   = o_x1  + (size_t)NE*BB*CIN2*HWD;       // [E][B][10][HWD]
    constexpr size_t o_w1   = o_t2  + (size_t)NE*BB*NHID*HWD;
    constexpr size_t o_b1   = o_w1   + 58320;
    constexpr size_t o_d1   = o_b1   + 324;
    constexpr size_t o_w2   = o_d1   + 43200;
    constexpr size_t o_b2   = o_w2   + 58320;
    constexpr size_t o_d2   = o_b2   + 324;
    constexpr size_t o_uw   = o_d2   + 21600;
    constexpr size_t o_bn1s = o_uw   + 15360;
    constexpr size_t o_bn1t = o_bn1s + NE*CIN2;
    constexpr size_t o_bn2s = o_bn1t + NE*CIN2;
    constexpr size_t o_bn2t = o_bn2s + NE*NHID;
    constexpr size_t o_bn5s = o_bn2t + NE*NHID;
    constexpr size_t o_bn5t = o_bn5s + NPART*NHID;
    constexpr size_t o_y    = o_bn5t + NPART*NHID;                  // [P][B][10][HWD]
    float* x1 = ws + o_x1;
    float* t2 = ws + o_t2;
    float* y  = ws + o_y;

    xpose_weights<<<dim3(772), 256, 0, stream>>>(
        off1_w, off1_b, dcn1_w, off2_w, off2_b, dcn2_w, upd_w,
        ws+o_w1, ws+o_b1, ws+o_d1, ws+o_w2, ws+o_b2, ws+o_d2, ws+o_uw);

    dcn_tiled<CIN2, true><<<dim3(36, BB, NE), 512, 0, stream>>>(
        nullptr, xp, esrc, edst, ws+o_w1, ws+o_b1, ws+o_d1,
        nullptr, nullptr, x1);

    bn_stats_flat<CIN2><<<dim3(NE*CIN2), 256, 0, stream>>>(
        x1, bn1_g, bn1_b, ws+o_bn1s, ws+o_bn1t);

    dcn_tiled<NHID, false><<<dim3(36, BB, NE), 512, 0, stream>>>(
        x1, nullptr, esrc, edst, ws+o_w2, ws+o_b2, ws+o_d2,
        ws+o_bn1s, ws+o_bn1t, t2);

    bn_stats_flat<NHID><<<dim3(NE*NHID), 256, 0, stream>>>(
        t2, bn2_g, bn2_b, ws+o_bn2s, ws+o_bn2t);

    mgq_kernel<<<dim3(36, BB, NPART), 256, 0, stream>>>(
        t2, ws+o_bn2s, ws+o_bn2t, out_w, out_b, aatt_w, aatt_b, xp, xh,
        att_w, att_b, du_w, du_b, dl_w, dl_b, esrc, edst,
        p_fea, ws+o_uw, y);

    bn_stats_flat<NHID><<<dim3(NPART*NHID), 256, 0, stream>>>(
        y, upd_g, upd_b, ws+o_bn5s, ws+o_bn5t);

    out_kernel<<<dim3(36, BB*NHID, NPART), 256, 0, stream>>>(
        y, ws+o_bn5s, ws+o_bn5t, outp);
}

// Round 11
// 290.742 us; speedup vs baseline: 1.6189x; 1.6189x over previous
//
#include <hip/hip_runtime.h>

// ---------------------------------------------------------------------------
// Part_Graph: deformable-conv message passing over a 6-node part graph.
// B=2, H=W=96, IN=256, HID=10, P=6, E=12, K=9 taps.  ALL I/O is float32.
// dcn: R9-proven 256-thread LDS-tiled kernel (scalar fmaf, rotation prefetch).
// mgq: fused msg+gate+q with 8-deep load batching.
// ---------------------------------------------------------------------------

#define NE 12
#define NPART 6
#define BB 2
#define HH 96
#define WW 96
#define HWD (HH*WW)          // 9216
#define CIN2 20              // 2*HID concat channels
#define NHID 10
#define NIN 256

// LDS tile geometry: 16x16 output tile, +-2 halo -> 20x20 box.
#define BOX 20
#define BCOL 21              // padded col stride (bank stagger)
#define PLANE (BOX*BCOL*4)   // floats per 4-channel plane = 1680

__device__ __forceinline__ float sigf(float x) { return 1.f / (1.f + __expf(-x)); }

// ---------------------------------------------------------------------------
// Weight transposition to hot-loop friendly layouts (fp32 -> fp32):
//   off*_wt : [e][t=9][c=20][o=27]   (conv: per tap, n[c] dot into om[o])
//   dcn*_wt : [e][k=9][c=20][o]      (sampling: per (k,c) matvec over o)
//   upd_wt  : [p][c=256][o=10]
// ---------------------------------------------------------------------------
__global__ __launch_bounds__(256)
void xpose_weights(const float* __restrict__ off1_w, const float* __restrict__ off1_b,
                   const float* __restrict__ dcn1_w,
                   const float* __restrict__ off2_w, const float* __restrict__ off2_b,
                   const float* __restrict__ dcn2_w,
                   const float* __restrict__ upd_w,
                   float* __restrict__ o1wt, float* __restrict__ o1b, float* __restrict__ d1wt,
                   float* __restrict__ o2wt, float* __restrict__ o2b, float* __restrict__ d2wt,
                   float* __restrict__ uwt)
{
    int idx = blockIdx.x * 256 + threadIdx.x;
    if (idx < 58320) {                       // off1_wt [e][t][c][27]
        int e = idx / 4860, r = idx % 4860;
        int t = r / 540, r2 = r % 540, c = r2 / 27, o = r2 % 27;
        o1wt[idx] = off1_w[((e*27 + o)*CIN2 + c)*9 + t];
        return;
    }
    idx -= 58320;
    if (idx < 324) { o1b[idx] = off1_b[idx]; return; }
    idx -= 324;
    if (idx < 43200) {                       // dcn1_wt [e][k][c][20]
        int e = idx / 3600, r = idx % 3600;
        int k = r / 400, r2 = r % 400, c = r2 / 20, o = r2 % 20;
        d1wt[idx] = dcn1_w[((e*20 + o)*20 + c)*9 + k];
        return;
    }
    idx -= 43200;
    if (idx < 58320) {                       // off2_wt [e][t][c][27]
        int e = idx / 4860, r = idx % 4860;
        int t = r / 540, r2 = r % 540, c = r2 / 27, o = r2 % 27;
        o2wt[idx] = off2_w[((e*27 + o)*CIN2 + c)*9 + t];
        return;
    }
    idx -= 58320;
    if (idx < 324) { o2b[idx] = off2_b[idx]; return; }
    idx -= 324;
    if (idx < 21600) {                       // dcn2_wt [e][k][c][10]
        int e = idx / 1800, r = idx % 1800;
        int k = r / 200, r2 = r % 200, c = r2 / 10, o = r2 % 10;
        d2wt[idx] = dcn2_w[((e*10 + o)*20 + c)*9 + k];
        return;
    }
    idx -= 21600;
    if (idx < 15360) {                       // upd_wt [p][c][10]
        int p = idx / 2560, r = idx % 2560, c = r / 10, o = r % 10;
        uwt[idx] = upd_w[(p*10 + o)*256 + c];
        return;
    }
}

// ---------------------------------------------------------------------------
// Fused, LDS-tiled DCNv2 layer (R9-proven).
// 16x16 px tile/block; 20x20 halo box, 20 ch as 5 float4-planes in LDS.
// ILP: rotation-prefetch with unroll(1) loops (bounded live set, no spill).
// grid: (36, B, E); 4 blocks/CU (33.6 KB LDS), VGPR cap 128.
// ---------------------------------------------------------------------------
template<int COUT, bool L1>
__global__ __launch_bounds__(256, 4)
void dcn_tiled(const float* __restrict__ xin_all,
               const float* __restrict__ xp,      // only for L1 gather
               const int* __restrict__ esrc, const int* __restrict__ edst,
               const float* __restrict__ wo_all,  // [E][9][20][27]
               const float* __restrict__ bo_all,  // [E][27]
               const float* __restrict__ wd_all,  // [E][9][20][COUT]
               const float* __restrict__ bnS, const float* __restrict__ bnT,
               float* __restrict__ out)
{
    const int b = blockIdx.y, e = blockIdx.z;
    const int ty0 = (blockIdx.x / 6) * 16, tx0 = (blockIdx.x % 6) * 16;
    const int tid = threadIdx.x;
    const int ly = tid >> 4, lx = tid & 15;
    const int h = ty0 + ly, w = tx0 + lx;
    const int r0 = ty0 - 2, c0 = tx0 - 2;          // staged box origin

    const float* __restrict__ xin = xin_all + (size_t)(e*BB + b)*CIN2*HWD;
    const float* __restrict__ wo  = wo_all + (size_t)e*9*CIN2*27;
    const float* __restrict__ bo  = bo_all + e*27;
    const float* __restrict__ wd  = wd_all + (size_t)e*9*CIN2*COUT;

    __shared__ float lds[5*PLANE];                 // 33.6 KB

    // ---- stage: 2000 float4 quads = 20ch x 20rows x 5 ----
    #pragma unroll 1
    for (int i = tid; i < 2000; i += 256) {
        int c   = i / 100;
        int rem = i - c*100;
        int rr  = rem / 5;
        int q   = rem - rr*5;
        const float* src;
        float sc = 1.f, sh = 0.f;
        if (L1) {
            int part = (c < NHID) ? esrc[e] : edst[e];
            int ch   = (c < NHID) ? c : c - NHID;
            src = xp + ((size_t)(part*BB + b)*NHID + ch)*HWD;
        } else {
            src = xin + (size_t)c*HWD;
            sc = bnS[e*CIN2 + c]; sh = bnT[e*CIN2 + c];
        }
        int y = r0 + rr, xb = c0 + 4*q;
        float4 v = make_float4(0.f, 0.f, 0.f, 0.f);
        if (y >= 0 && y < HH) {
            const float* row = src + y*WW;
            if (xb >= 0 && xb + 3 < WW) {
                v = *reinterpret_cast<const float4*>(row + xb);
            } else {
                if (xb+0 >= 0 && xb+0 < WW) v.x = row[xb+0];
                if (xb+1 >= 0 && xb+1 < WW) v.y = row[xb+1];
                if (xb+2 >= 0 && xb+2 < WW) v.z = row[xb+2];
                if (xb+3 >= 0 && xb+3 < WW) v.w = row[xb+3];
            }
            if (!L1) {      // pad stays 0 (matches zero-padding semantics)
                v.x = fmaxf(fmaf(v.x, sc, sh), 0.f);
                v.y = fmaxf(fmaf(v.y, sc, sh), 0.f);
                v.z = fmaxf(fmaf(v.z, sc, sh), 0.f);
                v.w = fmaxf(fmaf(v.w, sc, sh), 0.f);
            }
        }
        float* plane = lds + (c >> 2)*PLANE;
        int cl = c & 3;
        int base = (rr*BCOL + 4*q)*4 + cl;
        plane[base + 0]  = v.x;
        plane[base + 4]  = v.y;
        plane[base + 8]  = v.z;
        plane[base + 12] = v.w;
    }
    __syncthreads();

    // ---- offset conv: om[27] ----
    float om[27];
    #pragma unroll
    for (int o = 0; o < 27; o++) om[o] = bo[o];

    #pragma unroll
    for (int t = 0; t < 9; t++) {
        const int rr = ly + 2 + (t/3) - 1, cc = lx + 2 + (t%3) - 1;
        const int pix = (rr*BCOL + cc)*4;
        const float* wt = wo + t*CIN2*27;
        float4 n = *reinterpret_cast<const float4*>(&lds[pix]);   // chunk 0
        #pragma unroll 1
        for (int c4 = 0; c4 < 5; c4++) {
            float4 nn = make_float4(0.f, 0.f, 0.f, 0.f);
            if (c4 < 4)
                nn = *reinterpret_cast<const float4*>(&lds[(c4+1)*PLANE + pix]);
            const float* wc = wt + c4*4*27;
            #pragma unroll
            for (int j = 0; j < 4; j++) {
                float nv = (&n.x)[j];
                #pragma unroll
                for (int o = 0; o < 27; o++) om[o] = fmaf(nv, wc[j*27 + o], om[o]);
            }
            n = nn;
        }
    }

    // ---- deformable sampling + tap matvec ----
    float acc[COUT];
    #pragma unroll
    for (int o = 0; o < COUT; o++) acc[o] = 0.f;

    #pragma unroll
    for (int k = 0; k < 9; k++) {
        float m  = sigf(om[18 + k]);
        float ys = (float)(h + k/3 - 1) + om[2*k];
        float xs = (float)(w + k%3 - 1) + om[2*k + 1];
        float y0f = floorf(ys), x0f = floorf(xs);
        int iy = (int)y0f, ix = (int)x0f;
        float fy = ys - y0f, fx = xs - x0f;
        bool vy0 = (iy >= 0) && (iy < HH);
        bool vy1 = (iy >= -1) && (iy < HH-1);
        bool vx0 = (ix >= 0) && (ix < WW);
        bool vx1 = (ix >= -1) && (ix < WW-1);
        float w00 = (vy0 && vx0) ? (1.f-fy)*(1.f-fx)*m : 0.f;
        float w01 = (vy0 && vx1) ? (1.f-fy)*fx*m       : 0.f;
        float w10 = (vy1 && vx0) ? fy*(1.f-fx)*m       : 0.f;
        float w11 = (vy1 && vx1) ? fy*fx*m             : 0.f;
        int cy0 = min(max(iy,   0), HH-1), cy1 = min(max(iy+1, 0), HH-1);
        int cx0 = min(max(ix,   0), WW-1), cx1 = min(max(ix+1, 0), WW-1);
        const float* wk = wd + k*CIN2*COUT;

        bool staged = (cy0 >= r0) && (cy1 <= r0 + BOX-1) &&
                      (cx0 >= c0) && (cx1 <= c0 + BOX-1);
        if (staged) {
            const int p00 = ((cy0-r0)*BCOL + (cx0-c0))*4;
            const int p01 = ((cy0-r0)*BCOL + (cx1-c0))*4;
            const int p10 = ((cy1-r0)*BCOL + (cx0-c0))*4;
            const int p11 = ((cy1-r0)*BCOL + (cx1-c0))*4;
            // rotation prefetch: load chunk c4+1 while FMA-ing chunk c4
            float4 a  = *reinterpret_cast<const float4*>(lds + p00);
            float4 bq = *reinterpret_cast<const float4*>(lds + p01);
            float4 cq = *reinterpret_cast<const float4*>(lds + p10);
            float4 dq = *reinterpret_cast<const float4*>(lds + p11);
            #pragma unroll 1
            for (int c4 = 0; c4 < 5; c4++) {
                float4 a2 = make_float4(0.f,0.f,0.f,0.f);
                float4 b2 = a2, c2 = a2, d2 = a2;
                if (c4 < 4) {
                    const float* pl = lds + (c4+1)*PLANE;
                    a2 = *reinterpret_cast<const float4*>(pl + p00);
                    b2 = *reinterpret_cast<const float4*>(pl + p01);
                    c2 = *reinterpret_cast<const float4*>(pl + p10);
                    d2 = *reinterpret_cast<const float4*>(pl + p11);
                }
                const float* wc = wk + c4*4*COUT;
                #pragma unroll
                for (int j = 0; j < 4; j++) {
                    float s = w00*(&a.x)[j] + w01*(&bq.x)[j]
                            + w10*(&cq.x)[j] + w11*(&dq.x)[j];
                    #pragma unroll
                    for (int o = 0; o < COUT; o++)
                        acc[o] = fmaf(s, wc[j*COUT + o], acc[o]);
                }
                a = a2; bq = b2; cq = c2; dq = d2;
            }
        } else {
            int o00 = cy0*WW + cx0, o01 = cy0*WW + cx1;
            int o10 = cy1*WW + cx0, o11 = cy1*WW + cx1;
            #pragma unroll 1
            for (int c = 0; c < CIN2; c++) {
                const float* src;
                float sc = 1.f, sh = 0.f;
                if (L1) {
                    int part = (c < NHID) ? esrc[e] : edst[e];
                    int ch   = (c < NHID) ? c : c - NHID;
                    src = xp + ((size_t)(part*BB + b)*NHID + ch)*HWD;
                } else {
                    src = xin + (size_t)c*HWD;
                    sc = bnS[e*CIN2 + c]; sh = bnT[e*CIN2 + c];
                }
                float av = src[o00], bv = src[o01], cv = src[o10], dv = src[o11];
                if (!L1) {
                    av = fmaxf(fmaf(av, sc, sh), 0.f); bv = fmaxf(fmaf(bv, sc, sh), 0.f);
                    cv = fmaxf(fmaf(cv, sc, sh), 0.f); dv = fmaxf(fmaf(dv, sc, sh), 0.f);
                }
                float s = w00*av + w01*bv + w10*cv + w11*dv;
                const float* wc = wk + c*COUT;
                #pragma unroll
                for (int o = 0; o < COUT; o++) acc[o] = fmaf(s, wc[o], acc[o]);
            }
        }
    }

    float* op = out + ((size_t)(e*BB + b)*COUT)*HWD + h*WW + w;
    #pragma unroll
    for (int o = 0; o < COUT; o++) op[(size_t)o*HWD] = acc[o];
}

// ---------------------------------------------------------------------------
// BN statistics (training mode, biased var, eps=1e-5), folding gamma/beta:
//   scale = g*rstd, shift = beta - mean*scale
// ---------------------------------------------------------------------------
__device__ __forceinline__ void bn_finish(float s1, float s2, int n, float g, float bt,
                                          float* scale, float* shift, int idx)
{
    float mean = s1 / (float)n;
    float var  = fmaxf(s2 / (float)n - mean*mean, 0.f);
    float rs   = rsqrtf(var + 1e-5f);
    scale[idx] = g * rs;
    shift[idx] = bt - mean * g * rs;
}

// stats over flat layout [G][B][C][HWD]; one block per (g,c); grid = G*C
template<int C>
__global__ __launch_bounds__(256)
void bn_stats_flat(const float* __restrict__ x, const float* __restrict__ gamma,
                   const float* __restrict__ beta, float* __restrict__ scale,
                   float* __restrict__ shift)
{
    const int gc = blockIdx.x;
    const int g = gc / C, c = gc % C;
    const int N = BB * HWD;
    float s1 = 0.f, s2 = 0.f;
    for (int idx = threadIdx.x; idx < N; idx += 256) {
        int b = idx / HWD, p = idx % HWD;
        float v = x[((size_t)(g*BB + b)*C + c)*HWD + p];
        s1 += v; s2 += v*v;
    }
    __shared__ float r1[256], r2[256];
    r1[threadIdx.x] = s1; r2[threadIdx.x] = s2;
    __syncthreads();
    for (int s = 128; s > 0; s >>= 1) {
        if (threadIdx.x < s) { r1[threadIdx.x] += r1[threadIdx.x+s]; r2[threadIdx.x] += r2[threadIdx.x+s]; }
        __syncthreads();
    }
    if (threadIdx.x == 0)
        bn_finish(r1[0], r2[0], N, gamma[gc], beta[gc], scale, shift, gc);
}

// ---------------------------------------------------------------------------
// Fused msg + gate + q (scalar, MLP via 8-batched loads):
//   gate = 1 + decomp + self_att + sum_{e: dst==p} msg_e
//   msg_e = sigmoid(o_w.relu(bn2(t2_e)) + o_b) * (1 - sigmoid(a_w.xp[src]+a_b))
//   y[p,b,o,hw] = gate * sum_c p_fea[b,c,hw] * upd_wt[p,c,o]
// grid: (36, B, P)
// ---------------------------------------------------------------------------
__global__ __launch_bounds__(256)
void mgq_kernel(const float* __restrict__ t2all, const float* __restrict__ s2,
                const float* __restrict__ sh2, const float* __restrict__ o_w,
                const float* __restrict__ o_b, const float* __restrict__ a_w,
                const float* __restrict__ a_b, const float* __restrict__ xp,
                const float* __restrict__ xh,
                const float* __restrict__ att_w, const float* __restrict__ att_b,
                const float* __restrict__ du_w, const float* __restrict__ du_b,
                const float* __restrict__ dl_w, const float* __restrict__ dl_b,
                const int* __restrict__ esrc, const int* __restrict__ edst,
                const float* __restrict__ p_fea, const float* __restrict__ wq_all,
                float* __restrict__ y)
{
    int px = blockIdx.x * 256 + threadIdx.x;
    int b = blockIdx.y, p = blockIdx.z;

    // self-attention
    float s = att_b[p];
    #pragma unroll
    for (int c = 0; c < NHID; c++)
        s += xp[((size_t)(p*BB + b)*NHID + c)*HWD + px] * att_w[p*NHID + c];
    float satt = sigf(s);

    // half-body decomposition gate
    int hs = (p < 4) ? 0 : 1;
    const float* dw = (p < 4) ? du_w : dl_w;
    float d = (p < 4) ? du_b[0] : dl_b[0];
    #pragma unroll
    for (int c = 0; c < NHID; c++)
        d += xh[((size_t)(hs*BB + b)*NHID + c)*HWD + px] * dw[c];
    float dec = sigf(d);

    // incoming-edge messages (each part has exactly 2 in-edges)
    float xpp = 0.f;
    for (int e = 0; e < NE; e++) {
        if (edst[e] != p) continue;
        float sab = o_b[e];
        #pragma unroll
        for (int c = 0; c < NHID; c++) {
            float v = t2all[((size_t)(e*BB + b)*NHID + c)*HWD + px];
            v = fmaxf(fmaf(v, s2[e*NHID+c], sh2[e*NHID+c]), 0.f);
            sab += v * o_w[e*NHID + c];
        }
        int sp = esrc[e];
        float sa = a_b[e];
        #pragma unroll
        for (int c = 0; c < NHID; c++)
            sa += xp[((size_t)(sp*BB + b)*NHID + c)*HWD + px] * a_w[e*NHID + c];
        xpp += sigf(sab) * (1.f - sigf(sa));
    }
    float gate = 1.f + dec + satt + xpp;

    // 256 -> 10 projection; 8 loads in flight per iteration (MLP)
    const float* wq = wq_all + (size_t)p*NIN*NHID;     // [c][10]
    const float* pf = p_fea + (size_t)b*NIN*HWD + px;
    float acc[NHID];
    #pragma unroll
    for (int o = 0; o < NHID; o++) acc[o] = 0.f;
    for (int c = 0; c < NIN; c += 8) {
        float v0 = pf[(size_t)(c+0)*HWD];
        float v1 = pf[(size_t)(c+1)*HWD];
        float v2 = pf[(size_t)(c+2)*HWD];
        float v3 = pf[(size_t)(c+3)*HWD];
        float v4 = pf[(size_t)(c+4)*HWD];
        float v5 = pf[(size_t)(c+5)*HWD];
        float v6 = pf[(size_t)(c+6)*HWD];
        float v7 = pf[(size_t)(c+7)*HWD];
        const float* wc = wq + c*NHID;
        #pragma unroll
        for (int o = 0; o < NHID; o++) acc[o] = fmaf(v0, wc[o], acc[o]);
        #pragma unroll
        for (int o = 0; o < NHID; o++) acc[o] = fmaf(v1, wc[NHID + o], acc[o]);
        #pragma unroll
        for (int o = 0; o < NHID; o++) acc[o] = fmaf(v2, wc[2*NHID + o], acc[o]);
        #pragma unroll
        for (int o = 0; o < NHID; o++) acc[o] = fmaf(v3, wc[3*NHID + o], acc[o]);
        #pragma unroll
        for (int o = 0; o < NHID; o++) acc[o] = fmaf(v4, wc[4*NHID + o], acc[o]);
        #pragma unroll
        for (int o = 0; o < NHID; o++) acc[o] = fmaf(v5, wc[5*NHID + o], acc[o]);
        #pragma unroll
        for (int o = 0; o < NHID; o++) acc[o] = fmaf(v6, wc[6*NHID + o], acc[o]);
        #pragma unroll
        for (int o = 0; o < NHID; o++) acc[o] = fmaf(v7, wc[7*NHID + o], acc[o]);
    }
    float* yp = y + ((size_t)(p*BB + b)*NHID)*HWD + px;
    #pragma unroll
    for (int o = 0; o < NHID; o++) yp[(size_t)o*HWD] = acc[o] * gate;
}

// ---------------------------------------------------------------------------
// out = relu(bn5(y));   grid: (36, B*HID, P)
// ---------------------------------------------------------------------------
__global__ __launch_bounds__(256)
void out_kernel(const float* __restrict__ y, const float* __restrict__ s5,
                const float* __restrict__ t5, float* __restrict__ out)
{
    int px = blockIdx.x * 256 + threadIdx.x;
    int bo = blockIdx.y, p = blockIdx.z;
    int b = bo / NHID, o = bo % NHID;
    size_t idx = ((size_t)(p*BB + b)*NHID + o)*HWD + px;
    out[idx] = fmaxf(fmaf(y[idx], s5[p*NHID+o], t5[p*NHID+o]), 0.f);
}

// ---------------------------------------------------------------------------
// launcher
// ---------------------------------------------------------------------------
extern "C" void kernel_launch(void* const* d_in, const int* in_sizes, int n_in,
                              void* d_out, int out_size, void* d_ws, size_t ws_size,
                              hipStream_t stream)
{
    (void)in_sizes; (void)n_in; (void)out_size; (void)ws_size;

    const float* p_fea  = (const float*)d_in[0];
    const float* xp     = (const float*)d_in[1];
    const float* xh     = (const float*)d_in[2];
    const float* att_w  = (const float*)d_in[3];
    const float* att_b  = (const float*)d_in[4];
    const float* du_w   = (const float*)d_in[5];
    const float* du_b   = (const float*)d_in[6];
    const float* dl_w   = (const float*)d_in[7];
    const float* dl_b   = (const float*)d_in[8];
    const float* upd_w  = (const float*)d_in[9];
    const float* upd_g  = (const float*)d_in[10];
    const float* upd_b  = (const float*)d_in[11];
    const float* off1_w = (const float*)d_in[12];
    const float* off1_b = (const float*)d_in[13];
    const float* dcn1_w = (const float*)d_in[14];
    const float* bn1_g  = (const float*)d_in[15];
    const float* bn1_b  = (const float*)d_in[16];
    const float* off2_w = (const float*)d_in[17];
    const float* off2_b = (const float*)d_in[18];
    const float* dcn2_w = (const float*)d_in[19];
    const float* bn2_g  = (const float*)d_in[20];
    const float* bn2_b  = (const float*)d_in[21];
    const float* out_w  = (const float*)d_in[22];
    const float* out_b  = (const float*)d_in[23];
    const float* aatt_w = (const float*)d_in[24];
    const float* aatt_b = (const float*)d_in[25];
    const int* esrc     = (const int*)d_in[26];
    const int* edst     = (const int*)d_in[27];
    float* outp = (float*)d_out;
    float* ws = (float*)d_ws;

    // workspace layout (float offsets)
    constexpr size_t o_x1   = 0;                                    // [E][B][20][HWD]
    constexpr size_t o_t2   = o_x1  + (size_t)NE*BB*CIN2*HWD;       // [E][B][10][HWD]
    constexpr size_t o_w1   = o_t2  + (size_t)NE*BB*NHID*HWD;
    constexpr size_t o_b1   = o_w1   + 58320;
    constexpr size_t o_d1   = o_b1   + 324;
    constexpr size_t o_w2   = o_d1   + 43200;
    constexpr size_t o_b2   = o_w2   + 58320;
    constexpr size_t o_d2   = o_b2   + 324;
    constexpr size_t o_uw   = o_d2   + 21600;
    constexpr size_t o_bn1s = o_uw   + 15360;
    constexpr size_t o_bn1t = o_bn1s + NE*CIN2;
    constexpr size_t o_bn2s = o_bn1t + NE*CIN2;
    constexpr size_t o_bn2t = o_bn2s + NE*NHID;
    constexpr size_t o_bn5s = o_bn2t + NE*NHID;
    constexpr size_t o_bn5t = o_bn5s + NPART*NHID;
    constexpr size_t o_y    = o_bn5t + NPART*NHID;                  // [P][B][10][HWD]
    float* x1 = ws + o_x1;
    float* t2 = ws + o_t2;
    float* y  = ws + o_y;

    xpose_weights<<<dim3(772), 256, 0, stream>>>(
        off1_w, off1_b, dcn1_w, off2_w, off2_b, dcn2_w, upd_w,
        ws+o_w1, ws+o_b1, ws+o_d1, ws+o_w2, ws+o_b2, ws+o_d2, ws+o_uw);

    dcn_tiled<CIN2, true><<<dim3(36, BB, NE), 256, 0, stream>>>(
        nullptr, xp, esrc, edst, ws+o_w1, ws+o_b1, ws+o_d1,
        nullptr, nullptr, x1);

    bn_stats_flat<CIN2><<<dim3(NE*CIN2), 256, 0, stream>>>(
        x1, bn1_g, bn1_b, ws+o_bn1s, ws+o_bn1t);

    dcn_tiled<NHID, false><<<dim3(36, BB, NE), 256, 0, stream>>>(
        x1, nullptr, esrc, edst, ws+o_w2, ws+o_b2, ws+o_d2,
        ws+o_bn1s, ws+o_bn1t, t2);

    bn_stats_flat<NHID><<<dim3(NE*NHID), 256, 0, stream>>>(
        t2, bn2_g, bn2_b, ws+o_bn2s, ws+o_bn2t);

    mgq_kernel<<<dim3(36, BB, NPART), 256, 0, stream>>>(
        t2, ws+o_bn2s, ws+o_bn2t, out_w, out_b, aatt_w, aatt_b, xp, xh,
        att_w, att_b, du_w, du_b, dl_w, dl_b, esrc, edst,
        p_fea, ws+o_uw, y);

    bn_stats_flat<NHID><<<dim3(NPART*NHID), 256, 0, stream>>>(
        y, upd_g, upd_b, ws+o_bn5s, ws+o_bn5t);

    out_kernel<<<dim3(36, BB*NHID, NPART), 256, 0, stream>>>(
        y, ws+o_bn5s, ws+o_bn5t, outp);
}

// Round 12
// 226.090 us; speedup vs baseline: 2.0818x; 1.2860x over previous
//
#include <hip/hip_runtime.h>
#include <hip/hip_bf16.h>

// ---------------------------------------------------------------------------
// Part_Graph: deformable-conv message passing over a 6-node part graph.
// B=2, H=W=96, IN=256, HID=10, P=6, E=12, K=9 taps.  ALL I/O is float32.
// dcn: offset-conv via bf16 MFMA (16x16x32), sampling scalar on bf16 tile.
// ---------------------------------------------------------------------------

#define NE 12
#define NPART 6
#define BB 2
#define HH 96
#define WW 96
#define HWD (HH*WW)          // 9216
#define CIN2 20              // 2*HID concat channels
#define NHID 10
#define NIN 256

// LDS tile geometry: 16x16 output tile, +-2 halo -> 20x20 box.
#define BOX 20
#define BCOL 21              // pix = rr*BCOL + cc
#define NPIX (BOX*BCOL)      // 420
#define GHALF (NPIX*8)       // ushorts per 8-channel group = 3360

typedef __attribute__((ext_vector_type(8))) short s16x8;
typedef __attribute__((ext_vector_type(4))) float f32x4;

__device__ __forceinline__ float sigf(float x) { return 1.f / (1.f + __expf(-x)); }
__device__ __forceinline__ float bfbits2f(unsigned int u) {
    return __uint_as_float(u << 16);
}
__device__ __forceinline__ unsigned short f2bfbits(float v) {
    __hip_bfloat16 h = __float2bfloat16(v);
    return *reinterpret_cast<unsigned short*>(&h);
}

// ---------------------------------------------------------------------------
// Weight prep:
//   bf*  : [e][t=9][nt=2][lane=64][i=8] bf16 B-fragments for MFMA
//          value = W[k= (lane>>4)*8+i][col= nt*16+(lane&15)] (zero-padded)
//   b*   : [e][27] fp32 conv bias
//   d*wt : [e][k=9][c=20][COUT] fp32 sampling weights
//   uwt  : [p][c=256][o=10] fp32
// ---------------------------------------------------------------------------
__global__ __launch_bounds__(256)
void xpose_weights(const float* __restrict__ off1_w, const float* __restrict__ off1_b,
                   const float* __restrict__ dcn1_w,
                   const float* __restrict__ off2_w, const float* __restrict__ off2_b,
                   const float* __restrict__ dcn2_w,
                   const float* __restrict__ upd_w,
                   unsigned short* __restrict__ bf1, float* __restrict__ o1b,
                   float* __restrict__ d1wt,
                   unsigned short* __restrict__ bf2, float* __restrict__ o2b,
                   float* __restrict__ d2wt,
                   float* __restrict__ uwt)
{
    int idx = blockIdx.x * 256 + threadIdx.x;
    if (idx < 110592) {                      // bf1 [e][t][nt][lane][i]
        int e = idx / 9216, r = idx % 9216;
        int t = r / 1024, r2 = r % 1024;
        int nt = r2 / 512, r3 = r2 % 512;
        int lane = r3 / 8, i = r3 % 8;
        int k = (lane >> 4)*8 + i;
        int col = nt*16 + (lane & 15);
        float v = (k < CIN2 && col < 27) ? off1_w[((e*27 + col)*CIN2 + k)*9 + t] : 0.f;
        bf1[idx] = f2bfbits(v);
        return;
    }
    idx -= 110592;
    if (idx < 324) { o1b[idx] = off1_b[idx]; return; }
    idx -= 324;
    if (idx < 43200) {                       // d1wt [e][k][c][20]
        int e = idx / 3600, r = idx % 3600;
        int k = r / 400, r2 = r % 400, c = r2 / 20, o = r2 % 20;
        d1wt[idx] = dcn1_w[((e*20 + o)*20 + c)*9 + k];
        return;
    }
    idx -= 43200;
    if (idx < 110592) {                      // bf2
        int e = idx / 9216, r = idx % 9216;
        int t = r / 1024, r2 = r % 1024;
        int nt = r2 / 512, r3 = r2 % 512;
        int lane = r3 / 8, i = r3 % 8;
        int k = (lane >> 4)*8 + i;
        int col = nt*16 + (lane & 15);
        float v = (k < CIN2 && col < 27) ? off2_w[((e*27 + col)*CIN2 + k)*9 + t] : 0.f;
        bf2[idx] = f2bfbits(v);
        return;
    }
    idx -= 110592;
    if (idx < 324) { o2b[idx] = off2_b[idx]; return; }
    idx -= 324;
    if (idx < 21600) {                       // d2wt [e][k][c][10]
        int e = idx / 1800, r = idx % 1800;
        int k = r / 200, r2 = r % 200, c = r2 / 10, o = r2 % 10;
        d2wt[idx] = dcn2_w[((e*10 + o)*20 + c)*9 + k];
        return;
    }
    idx -= 21600;
    if (idx < 15360) {                       // upd_wt [p][c][10]
        int p = idx / 2560, r = idx % 2560, c = r / 10, o = r % 10;
        uwt[idx] = upd_w[(p*10 + o)*256 + c];
        return;
    }
}

// ---------------------------------------------------------------------------
// Fused DCNv2 layer: bf16 MFMA offset-conv + scalar deformable sampling.
// 16x16 px tile/block (256 threads = 4 waves); LDS:
//   ldsb: 3 groups x [420 pix][8 ch] bf16 = 20.2 KB   (tile, ch 20-23 zero)
//   omb : [256 px][32] bf16 om buffer    = 16.4 KB
// grid: (36, B, E); 4 blocks/CU.
// ---------------------------------------------------------------------------
template<int COUT, bool L1>
__global__ __launch_bounds__(256, 4)
void dcn_tiled(const float* __restrict__ xin_all,
               const float* __restrict__ xp,        // only for L1 gather
               const int* __restrict__ esrc, const int* __restrict__ edst,
               const unsigned short* __restrict__ bfr_all, // [E][9][2][64][8]
               const float* __restrict__ bo_all,    // [E][27]
               const float* __restrict__ wd_all,    // [E][9][20][COUT]
               const float* __restrict__ bnS, const float* __restrict__ bnT,
               float* __restrict__ out)
{
    const int b = blockIdx.y, e = blockIdx.z;
    const int ty0 = (blockIdx.x / 6) * 16, tx0 = (blockIdx.x % 6) * 16;
    const int tid = threadIdx.x;
    const int ly = tid >> 4, lx = tid & 15;
    const int h = ty0 + ly, w = tx0 + lx;
    const int r0 = ty0 - 2, c0 = tx0 - 2;            // staged box origin

    const float* __restrict__ xin = xin_all + (size_t)(e*BB + b)*CIN2*HWD;
    const float* __restrict__ bo  = bo_all + e*27;
    const float* __restrict__ wd  = wd_all + (size_t)e*9*CIN2*COUT;
    const unsigned short* __restrict__ bfr = bfr_all + (size_t)e*9216;

    __shared__ unsigned short ldsb[3*GHALF];         // 20160 ushorts
    __shared__ unsigned short omb[256*32];           // 8192 ushorts

    // ---- stage: 1260 units = 3 groups x 420 pix, 8 bf16 ch per unit ----
    #pragma unroll 1
    for (int i = tid; i < 3*NPIX; i += 256) {
        int g = i / NPIX;
        int pix = i - g*NPIX;
        int rr = pix / BCOL, cc = pix - rr*BCOL;
        int y = r0 + rr, x = c0 + cc;
        bool inb = (y >= 0 && y < HH && x >= 0 && x < WW);
        int hw = y*WW + x;
        unsigned int dpk[4];
        #pragma unroll
        for (int jj = 0; jj < 4; jj++) {
            unsigned int packed = 0;
            #pragma unroll
            for (int hl = 0; hl < 2; hl++) {
                int c = g*8 + jj*2 + hl;
                float v = 0.f;
                if (inb && c < CIN2) {
                    if (L1) {
                        int part = (c < NHID) ? esrc[e] : edst[e];
                        int ch   = (c < NHID) ? c : c - NHID;
                        v = xp[((size_t)(part*BB + b)*NHID + ch)*HWD + hw];
                    } else {
                        v = xin[(size_t)c*HWD + hw];
                        v = fmaxf(fmaf(v, bnS[e*CIN2 + c], bnT[e*CIN2 + c]), 0.f);
                    }
                }
                packed |= ((unsigned int)f2bfbits(v)) << (16*hl);
            }
            dpk[jj] = packed;
        }
        *reinterpret_cast<uint4*>(&ldsb[g*GHALF + pix*8]) =
            make_uint4(dpk[0], dpk[1], dpk[2], dpk[3]);
    }
    __syncthreads();

    // ---- offset conv via MFMA: per wave 4 M-tiles x 2 N-tiles x 9 taps ----
    {
        const int lane = tid & 63;
        const int wv   = tid >> 6;
        const int lrow = lane & 15;                  // A row / C col
        const int lkg  = lane >> 4;                  // k-group
        const int gsel = (lkg < 3) ? lkg : 2;        // k>=24 lanes: B rows are 0
        f32x4 acc[4][2];
        #pragma unroll
        for (int mt = 0; mt < 4; mt++)
            #pragma unroll
            for (int nt = 0; nt < 2; nt++)
                acc[mt][nt] = f32x4{0.f, 0.f, 0.f, 0.f};

        const s16x8* ap = reinterpret_cast<const s16x8*>(&ldsb[gsel*GHALF]);
        #pragma unroll 1
        for (int t = 0; t < 9; t++) {
            const s16x8* bp = reinterpret_cast<const s16x8*>(bfr + t*1024);
            s16x8 b0 = bp[lane];
            s16x8 b1 = bp[64 + lane];
            int dty = t/3 - 1, dtx = t - (t/3)*3 - 1;
            #pragma unroll
            for (int mt = 0; mt < 4; mt++) {
                int pxl = wv*64 + mt*16 + lrow;
                int pix = ((pxl >> 4) + 2 + dty)*BCOL + ((pxl & 15) + 2 + dtx);
                s16x8 a = ap[pix];
                acc[mt][0] = __builtin_amdgcn_mfma_f32_16x16x32_bf16(a, b0, acc[mt][0], 0, 0, 0);
                acc[mt][1] = __builtin_amdgcn_mfma_f32_16x16x32_bf16(a, b1, acc[mt][1], 0, 0, 0);
            }
        }
        // write om tiles (verified C/D layout: col=lane&15, row=(lane>>4)*4+r)
        #pragma unroll
        for (int mt = 0; mt < 4; mt++) {
            #pragma unroll
            for (int nt = 0; nt < 2; nt++) {
                #pragma unroll
                for (int r = 0; r < 4; r++) {
                    int row = wv*64 + mt*16 + lkg*4 + r;
                    int col = nt*16 + lrow;
                    omb[row*32 + col] = f2bfbits(acc[mt][nt][r]);
                }
            }
        }
    }
    __syncthreads();

    // ---- unpack this pixel's om[27] (+bias) ----
    float om[27];
    {
        const uint4* orow = reinterpret_cast<const uint4*>(&omb[tid*32]);
        uint4 u0 = orow[0], u1 = orow[1], u2 = orow[2], u3 = orow[3];
        unsigned int dw[16] = {u0.x,u0.y,u0.z,u0.w, u1.x,u1.y,u1.z,u1.w,
                               u2.x,u2.y,u2.z,u2.w, u3.x,u3.y,u3.z,u3.w};
        #pragma unroll
        for (int o = 0; o < 27; o++) {
            unsigned int bits = (o & 1) ? (dw[o>>1] >> 16) : (dw[o>>1] & 0xffffu);
            om[o] = bfbits2f(bits) + bo[o];
        }
    }

    // ---- deformable sampling + tap matvec (scalar, bf16 tile) ----
    float acc[COUT];
    #pragma unroll
    for (int o = 0; o < COUT; o++) acc[o] = 0.f;

    #pragma unroll
    for (int k = 0; k < 9; k++) {
        float m  = sigf(om[18 + k]);
        float ys = (float)(h + k/3 - 1) + om[2*k];
        float xs = (float)(w + k%3 - 1) + om[2*k + 1];
        float y0f = floorf(ys), x0f = floorf(xs);
        int iy = (int)y0f, ix = (int)x0f;
        float fy = ys - y0f, fx = xs - x0f;
        bool vy0 = (iy >= 0) && (iy < HH);
        bool vy1 = (iy >= -1) && (iy < HH-1);
        bool vx0 = (ix >= 0) && (ix < WW);
        bool vx1 = (ix >= -1) && (ix < WW-1);
        float w00 = (vy0 && vx0) ? (1.f-fy)*(1.f-fx)*m : 0.f;
        float w01 = (vy0 && vx1) ? (1.f-fy)*fx*m       : 0.f;
        float w10 = (vy1 && vx0) ? fy*(1.f-fx)*m       : 0.f;
        float w11 = (vy1 && vx1) ? fy*fx*m             : 0.f;
        int cy0 = min(max(iy,   0), HH-1), cy1 = min(max(iy+1, 0), HH-1);
        int cx0 = min(max(ix,   0), WW-1), cx1 = min(max(ix+1, 0), WW-1);
        const float* wk = wd + k*CIN2*COUT;

        bool staged = (cy0 >= r0) && (cy1 <= r0 + BOX-1) &&
                      (cx0 >= c0) && (cx1 <= c0 + BOX-1);
        if (staged) {
            const int p00 = (cy0-r0)*BCOL + (cx0-c0);
            const int p01 = (cy0-r0)*BCOL + (cx1-c0);
            const int p10 = (cy1-r0)*BCOL + (cx0-c0);
            const int p11 = (cy1-r0)*BCOL + (cx1-c0);
            #pragma unroll
            for (int g = 0; g < 3; g++) {
                const s16x8* gp = reinterpret_cast<const s16x8*>(&ldsb[g*GHALF]);
                s16x8 a8 = gp[p00], b8 = gp[p01], c8 = gp[p10], d8 = gp[p11];
                #pragma unroll
                for (int j = 0; j < 8; j++) {
                    int c = g*8 + j;
                    if (c < CIN2) {
                        float av = bfbits2f((unsigned short)a8[j]);
                        float bv = bfbits2f((unsigned short)b8[j]);
                        float cv = bfbits2f((unsigned short)c8[j]);
                        float dv = bfbits2f((unsigned short)d8[j]);
                        float s = w00*av + w01*bv + w10*cv + w11*dv;
                        const float* wc = wk + c*COUT;
                        #pragma unroll
                        for (int o = 0; o < COUT; o++)
                            acc[o] = fmaf(s, wc[o], acc[o]);
                    }
                }
            }
        } else {
            int o00 = cy0*WW + cx0, o01 = cy0*WW + cx1;
            int o10 = cy1*WW + cx0, o11 = cy1*WW + cx1;
            #pragma unroll 1
            for (int c = 0; c < CIN2; c++) {
                const float* src;
                float sc = 1.f, sh = 0.f;
                if (L1) {
                    int part = (c < NHID) ? esrc[e] : edst[e];
                    int ch   = (c < NHID) ? c : c - NHID;
                    src = xp + ((size_t)(part*BB + b)*NHID + ch)*HWD;
                } else {
                    src = xin + (size_t)c*HWD;
                    sc = bnS[e*CIN2 + c]; sh = bnT[e*CIN2 + c];
                }
                float av = src[o00], bv = src[o01], cv = src[o10], dv = src[o11];
                if (!L1) {
                    av = fmaxf(fmaf(av, sc, sh), 0.f); bv = fmaxf(fmaf(bv, sc, sh), 0.f);
                    cv = fmaxf(fmaf(cv, sc, sh), 0.f); dv = fmaxf(fmaf(dv, sc, sh), 0.f);
                }
                float s = w00*av + w01*bv + w10*cv + w11*dv;
                const float* wc = wk + c*COUT;
                #pragma unroll
                for (int o = 0; o < COUT; o++) acc[o] = fmaf(s, wc[o], acc[o]);
            }
        }
    }

    float* op = out + ((size_t)(e*BB + b)*COUT)*HWD + h*WW + w;
    #pragma unroll
    for (int o = 0; o < COUT; o++) op[(size_t)o*HWD] = acc[o];
}

// ---------------------------------------------------------------------------
// BN statistics (training mode, biased var, eps=1e-5), folding gamma/beta.
// ---------------------------------------------------------------------------
__device__ __forceinline__ void bn_finish(float s1, float s2, int n, float g, float bt,
                                          float* scale, float* shift, int idx)
{
    float mean = s1 / (float)n;
    float var  = fmaxf(s2 / (float)n - mean*mean, 0.f);
    float rs   = rsqrtf(var + 1e-5f);
    scale[idx] = g * rs;
    shift[idx] = bt - mean * g * rs;
}

template<int C>
__global__ __launch_bounds__(256)
void bn_stats_flat(const float* __restrict__ x, const float* __restrict__ gamma,
                   const float* __restrict__ beta, float* __restrict__ scale,
                   float* __restrict__ shift)
{
    const int gc = blockIdx.x;
    const int g = gc / C, c = gc % C;
    const int N = BB * HWD;
    float s1 = 0.f, s2 = 0.f;
    for (int idx = threadIdx.x; idx < N; idx += 256) {
        int b = idx / HWD, p = idx % HWD;
        float v = x[((size_t)(g*BB + b)*C + c)*HWD + p];
        s1 += v; s2 += v*v;
    }
    __shared__ float r1[256], r2[256];
    r1[threadIdx.x] = s1; r2[threadIdx.x] = s2;
    __syncthreads();
    for (int s = 128; s > 0; s >>= 1) {
        if (threadIdx.x < s) { r1[threadIdx.x] += r1[threadIdx.x+s]; r2[threadIdx.x] += r2[threadIdx.x+s]; }
        __syncthreads();
    }
    if (threadIdx.x == 0)
        bn_finish(r1[0], r2[0], N, gamma[gc], beta[gc], scale, shift, gc);
}

// ---------------------------------------------------------------------------
// Fused msg + gate + q (scalar, MLP via 8-batched loads).  grid: (36, B, P)
// ---------------------------------------------------------------------------
__global__ __launch_bounds__(256)
void mgq_kernel(const float* __restrict__ t2all, const float* __restrict__ s2,
                const float* __restrict__ sh2, const float* __restrict__ o_w,
                const float* __restrict__ o_b, const float* __restrict__ a_w,
                const float* __restrict__ a_b, const float* __restrict__ xp,
                const float* __restrict__ xh,
                const float* __restrict__ att_w, const float* __restrict__ att_b,
                const float* __restrict__ du_w, const float* __restrict__ du_b,
                const float* __restrict__ dl_w, const float* __restrict__ dl_b,
                const int* __restrict__ esrc, const int* __restrict__ edst,
                const float* __restrict__ p_fea, const float* __restrict__ wq_all,
                float* __restrict__ y)
{
    int px = blockIdx.x * 256 + threadIdx.x;
    int b = blockIdx.y, p = blockIdx.z;

    float s = att_b[p];
    #pragma unroll
    for (int c = 0; c < NHID; c++)
        s += xp[((size_t)(p*BB + b)*NHID + c)*HWD + px] * att_w[p*NHID + c];
    float satt = sigf(s);

    int hs = (p < 4) ? 0 : 1;
    const float* dw = (p < 4) ? du_w : dl_w;
    float d = (p < 4) ? du_b[0] : dl_b[0];
    #pragma unroll
    for (int c = 0; c < NHID; c++)
        d += xh[((size_t)(hs*BB + b)*NHID + c)*HWD + px] * dw[c];
    float dec = sigf(d);

    float xpp = 0.f;
    for (int e = 0; e < NE; e++) {
        if (edst[e] != p) continue;
        float sab = o_b[e];
        #pragma unroll
        for (int c = 0; c < NHID; c++) {
            float v = t2all[((size_t)(e*BB + b)*NHID + c)*HWD + px];
            v = fmaxf(fmaf(v, s2[e*NHID+c], sh2[e*NHID+c]), 0.f);
            sab += v * o_w[e*NHID + c];
        }
        int sp = esrc[e];
        float sa = a_b[e];
        #pragma unroll
        for (int c = 0; c < NHID; c++)
            sa += xp[((size_t)(sp*BB + b)*NHID + c)*HWD + px] * a_w[e*NHID + c];
        xpp += sigf(sab) * (1.f - sigf(sa));
    }
    float gate = 1.f + dec + satt + xpp;

    const float* wq = wq_all + (size_t)p*NIN*NHID;
    const float* pf = p_fea + (size_t)b*NIN*HWD + px;
    float acc[NHID];
    #pragma unroll
    for (int o = 0; o < NHID; o++) acc[o] = 0.f;
    for (int c = 0; c < NIN; c += 8) {
        float v0 = pf[(size_t)(c+0)*HWD];
        float v1 = pf[(size_t)(c+1)*HWD];
        float v2 = pf[(size_t)(c+2)*HWD];
        float v3 = pf[(size_t)(c+3)*HWD];
        float v4 = pf[(size_t)(c+4)*HWD];
        float v5 = pf[(size_t)(c+5)*HWD];
        float v6 = pf[(size_t)(c+6)*HWD];
        float v7 = pf[(size_t)(c+7)*HWD];
        const float* wc = wq + c*NHID;
        #pragma unroll
        for (int o = 0; o < NHID; o++) acc[o] = fmaf(v0, wc[o], acc[o]);
        #pragma unroll
        for (int o = 0; o < NHID; o++) acc[o] = fmaf(v1, wc[NHID + o], acc[o]);
        #pragma unroll
        for (int o = 0; o < NHID; o++) acc[o] = fmaf(v2, wc[2*NHID + o], acc[o]);
        #pragma unroll
        for (int o = 0; o < NHID; o++) acc[o] = fmaf(v3, wc[3*NHID + o], acc[o]);
        #pragma unroll
        for (int o = 0; o < NHID; o++) acc[o] = fmaf(v4, wc[4*NHID + o], acc[o]);
        #pragma unroll
        for (int o = 0; o < NHID; o++) acc[o] = fmaf(v5, wc[5*NHID + o], acc[o]);
        #pragma unroll
        for (int o = 0; o < NHID; o++) acc[o] = fmaf(v6, wc[6*NHID + o], acc[o]);
        #pragma unroll
        for (int o = 0; o < NHID; o++) acc[o] = fmaf(v7, wc[7*NHID + o], acc[o]);
    }
    float* yp = y + ((size_t)(p*BB + b)*NHID)*HWD + px;
    #pragma unroll
    for (int o = 0; o < NHID; o++) yp[(size_t)o*HWD] = acc[o] * gate;
}

// ---------------------------------------------------------------------------
// out = relu(bn5(y));   grid: (36, B*HID, P)
// ---------------------------------------------------------------------------
__global__ __launch_bounds__(256)
void out_kernel(const float* __restrict__ y, const float* __restrict__ s5,
                const float* __restrict__ t5, float* __restrict__ out)
{
    int px = blockIdx.x * 256 + threadIdx.x;
    int bo = blockIdx.y, p = blockIdx.z;
    int b = bo / NHID, o = bo % NHID;
    size_t idx = ((size_t)(p*BB + b)*NHID + o)*HWD + px;
    out[idx] = fmaxf(fmaf(y[idx], s5[p*NHID+o], t5[p*NHID+o]), 0.f);
}

// ---------------------------------------------------------------------------
// launcher
// ---------------------------------------------------------------------------
extern "C" void kernel_launch(void* const* d_in, const int* in_sizes, int n_in,
                              void* d_out, int out_size, void* d_ws, size_t ws_size,
                              hipStream_t stream)
{
    (void)in_sizes; (void)n_in; (void)out_size; (void)ws_size;

    const float* p_fea  = (const float*)d_in[0];
    const float* xp     = (const float*)d_in[1];
    const float* xh     = (const float*)d_in[2];
    const float* att_w  = (const float*)d_in[3];
    const float* att_b  = (const float*)d_in[4];
    const float* du_w   = (const float*)d_in[5];
    const float* du_b   = (const float*)d_in[6];
    const float* dl_w   = (const float*)d_in[7];
    const float* dl_b   = (const float*)d_in[8];
    const float* upd_w  = (const float*)d_in[9];
    const float* upd_g  = (const float*)d_in[10];
    const float* upd_b  = (const float*)d_in[11];
    const float* off1_w = (const float*)d_in[12];
    const float* off1_b = (const float*)d_in[13];
    const float* dcn1_w = (const float*)d_in[14];
    const float* bn1_g  = (const float*)d_in[15];
    const float* bn1_b  = (const float*)d_in[16];
    const float* off2_w = (const float*)d_in[17];
    const float* off2_b = (const float*)d_in[18];
    const float* dcn2_w = (const float*)d_in[19];
    const float* bn2_g  = (const float*)d_in[20];
    const float* bn2_b  = (const float*)d_in[21];
    const float* out_w  = (const float*)d_in[22];
    const float* out_b  = (const float*)d_in[23];
    const float* aatt_w = (const float*)d_in[24];
    const float* aatt_b = (const float*)d_in[25];
    const int* esrc     = (const int*)d_in[26];
    const int* edst     = (const int*)d_in[27];
    float* outp = (float*)d_out;
    float* ws = (float*)d_ws;

    // workspace layout (float offsets; bf-frag arrays are ushort, 2/float)
    constexpr size_t o_x1   = 0;                                    // [E][B][20][HWD]
    constexpr size_t o_t2   = o_x1  + (size_t)NE*BB*CIN2*HWD;       // [E][B][10][HWD]
    constexpr size_t o_bf1  = o_t2  + (size_t)NE*BB*NHID*HWD;       // 110592 ushort
    constexpr size_t o_b1   = o_bf1  + 55296;
    constexpr size_t o_d1   = o_b1   + 324;
    constexpr size_t o_bf2  = o_d1   + 43200;                       // 110592 ushort
    constexpr size_t o_b2   = o_bf2  + 55296;
    constexpr size_t o_d2   = o_b2   + 324;
    constexpr size_t o_uw   = o_d2   + 21600;
    constexpr size_t o_bn1s = o_uw   + 15360;
    constexpr size_t o_bn1t = o_bn1s + NE*CIN2;
    constexpr size_t o_bn2s = o_bn1t + NE*CIN2;
    constexpr size_t o_bn2t = o_bn2s + NE*NHID;
    constexpr size_t o_bn5s = o_bn2t + NE*NHID;
    constexpr size_t o_bn5t = o_bn5s + NPART*NHID;
    constexpr size_t o_y    = o_bn5t + NPART*NHID;                  // [P][B][10][HWD]
    float* x1 = ws + o_x1;
    float* t2 = ws + o_t2;
    float* y  = ws + o_y;
    unsigned short* bf1 = (unsigned short*)(ws + o_bf1);
    unsigned short* bf2 = (unsigned short*)(ws + o_bf2);

    // 110592+324+43200+110592+324+21600+15360 = 301992 items -> 1180 blocks
    xpose_weights<<<dim3(1180), 256, 0, stream>>>(
        off1_w, off1_b, dcn1_w, off2_w, off2_b, dcn2_w, upd_w,
        bf1, ws+o_b1, ws+o_d1, bf2, ws+o_b2, ws+o_d2, ws+o_uw);

    dcn_tiled<CIN2, true><<<dim3(36, BB, NE), 256, 0, stream>>>(
        nullptr, xp, esrc, edst, bf1, ws+o_b1, ws+o_d1,
        nullptr, nullptr, x1);

    bn_stats_flat<CIN2><<<dim3(NE*CIN2), 256, 0, stream>>>(
        x1, bn1_g, bn1_b, ws+o_bn1s, ws+o_bn1t);

    dcn_tiled<NHID, false><<<dim3(36, BB, NE), 256, 0, stream>>>(
        x1, nullptr, esrc, edst, bf2, ws+o_b2, ws+o_d2,
        ws+o_bn1s, ws+o_bn1t, t2);

    bn_stats_flat<NHID><<<dim3(NE*NHID), 256, 0, stream>>>(
        t2, bn2_g, bn2_b, ws+o_bn2s, ws+o_bn2t);

    mgq_kernel<<<dim3(36, BB, NPART), 256, 0, stream>>>(
        t2, ws+o_bn2s, ws+o_bn2t, out_w, out_b, aatt_w, aatt_b, xp, xh,
        att_w, att_b, du_w, du_b, dl_w, dl_b, esrc, edst,
        p_fea, ws+o_uw, y);

    bn_stats_flat<NHID><<<dim3(NPART*NHID), 256, 0, stream>>>(
        y, upd_g, upd_b, ws+o_bn5s, ws+o_bn5t);

    out_kernel<<<dim3(36, BB*NHID, NPART), 256, 0, stream>>>(
        y, ws+o_bn5s, ws+o_bn5t, outp);
}

// Round 13
// 191.869 us; speedup vs baseline: 2.4531x; 1.1784x over previous
//
#include <hip/hip_runtime.h>
#include <hip/hip_bf16.h>

// ---------------------------------------------------------------------------
// Part_Graph: deformable-conv message passing over a 6-node part graph.
// B=2, H=W=96, IN=256, HID=10, P=6, E=12, K=9 taps.  ALL I/O is float32.
// dcn: offset-conv AND sampling tap-matvec both via bf16 MFMA (16x16x32).
// ---------------------------------------------------------------------------

#define NE 12
#define NPART 6
#define BB 2
#define HH 96
#define WW 96
#define HWD (HH*WW)          // 9216
#define CIN2 20              // 2*HID concat channels
#define NHID 10
#define NIN 256

// LDS tile geometry: 16x16 output tile, +-2 halo -> 20x20 box.
#define BOX 20
#define BCOL 21              // pix = rr*BCOL + cc
#define NPIX (BOX*BCOL)      // 420
#define GHALF (NPIX*8)       // ushorts per 8-channel group = 3360
#define SROW 40              // s-tile row stride (ushorts): 80 B, 16B-aligned

typedef __attribute__((ext_vector_type(8))) short s16x8;
typedef __attribute__((ext_vector_type(4))) float f32x4;

__device__ __forceinline__ float sigf(float x) { return 1.f / (1.f + __expf(-x)); }
__device__ __forceinline__ float bfbits2f(unsigned int u) {
    return __uint_as_float(u << 16);
}
__device__ __forceinline__ unsigned short f2bfbits(float v) {
    __hip_bfloat16 h = __float2bfloat16(v);
    return *reinterpret_cast<unsigned short*>(&h);
}

// ---------------------------------------------------------------------------
// Weight prep (bf16 MFMA B-fragments + fp32 bias + fp32 upd):
//   bf*  : [e][t=9][nt=2][lane=64][i=8]  conv weights
//          value = Woff[k=(lane>>4)*8+i][col=nt*16+(lane&15)]  (zero-padded)
//   ws1  : [e][t=9][nt=2][lane=64][i=8]  sampling weights L1 (COUT=20)
//   ws2  : [e][t=9][nt=1][lane=64][i=8]  sampling weights L2 (COUT=10)
//          value = Wd[c=(lane>>4)*8+i][o=nt*16+(lane&15)]      (zero-padded)
//   b*   : [e][27] fp32 conv bias;  uwt: [p][c=256][o=10] fp32
// ---------------------------------------------------------------------------
__global__ __launch_bounds__(256)
void xpose_weights(const float* __restrict__ off1_w, const float* __restrict__ off1_b,
                   const float* __restrict__ dcn1_w,
                   const float* __restrict__ off2_w, const float* __restrict__ off2_b,
                   const float* __restrict__ dcn2_w,
                   const float* __restrict__ upd_w,
                   unsigned short* __restrict__ bf1, float* __restrict__ o1b,
                   unsigned short* __restrict__ ws1,
                   unsigned short* __restrict__ bf2, float* __restrict__ o2b,
                   unsigned short* __restrict__ ws2,
                   float* __restrict__ uwt)
{
    int idx = blockIdx.x * 256 + threadIdx.x;
    if (idx < 110592) {                      // bf1 [e][t][nt][lane][i]
        int e = idx / 9216, r = idx % 9216;
        int t = r / 1024, r2 = r % 1024;
        int nt = r2 / 512, r3 = r2 % 512;
        int lane = r3 / 8, i = r3 % 8;
        int k = (lane >> 4)*8 + i;
        int col = nt*16 + (lane & 15);
        float v = (k < CIN2 && col < 27) ? off1_w[((e*27 + col)*CIN2 + k)*9 + t] : 0.f;
        bf1[idx] = f2bfbits(v);
        return;
    }
    idx -= 110592;
    if (idx < 324) { o1b[idx] = off1_b[idx]; return; }
    idx -= 324;
    if (idx < 110592) {                      // ws1 [e][t][nt][lane][i]  (COUT=20)
        int e = idx / 9216, r = idx % 9216;
        int t = r / 1024, r2 = r % 1024;
        int nt = r2 / 512, r3 = r2 % 512;
        int lane = r3 / 8, i = r3 % 8;
        int c = (lane >> 4)*8 + i;
        int o = nt*16 + (lane & 15);
        float v = (c < CIN2 && o < CIN2) ? dcn1_w[((e*20 + o)*CIN2 + c)*9 + t] : 0.f;
        ws1[idx] = f2bfbits(v);
        return;
    }
    idx -= 110592;
    if (idx < 110592) {                      // bf2
        int e = idx / 9216, r = idx % 9216;
        int t = r / 1024, r2 = r % 1024;
        int nt = r2 / 512, r3 = r2 % 512;
        int lane = r3 / 8, i = r3 % 8;
        int k = (lane >> 4)*8 + i;
        int col = nt*16 + (lane & 15);
        float v = (k < CIN2 && col < 27) ? off2_w[((e*27 + col)*CIN2 + k)*9 + t] : 0.f;
        bf2[idx] = f2bfbits(v);
        return;
    }
    idx -= 110592;
    if (idx < 324) { o2b[idx] = off2_b[idx]; return; }
    idx -= 324;
    if (idx < 55296) {                       // ws2 [e][t][1][lane][i]  (COUT=10)
        int e = idx / 4608, r = idx % 4608;
        int t = r / 512, r3 = r % 512;
        int lane = r3 / 8, i = r3 % 8;
        int c = (lane >> 4)*8 + i;
        int o = lane & 15;
        float v = (c < CIN2 && o < NHID) ? dcn2_w[((e*10 + o)*CIN2 + c)*9 + t] : 0.f;
        ws2[idx] = f2bfbits(v);
        return;
    }
    idx -= 55296;
    if (idx < 15360) {                       // upd_wt [p][c][10]
        int p = idx / 2560, r = idx % 2560, c = r / 10, o = r % 10;
        uwt[idx] = upd_w[(p*10 + o)*256 + c];
        return;
    }
}

// ---------------------------------------------------------------------------
// Fused DCNv2 layer: MFMA offset-conv + MFMA sampling matvec.
// 256 threads = 4 waves; LDS: ldsb 20.2 KB (bf16 tile) + stile 20.5 KB
// (conv-om buffer, then per-tap s-tile) = 40.6 KB -> 4 blocks/CU.
// grid: (36, B, E)
// ---------------------------------------------------------------------------
template<int COUT, bool L1>
__global__ __launch_bounds__(256, 4)
void dcn_tiled(const float* __restrict__ xin_all,
               const float* __restrict__ xp,        // only for L1 gather
               const int* __restrict__ esrc, const int* __restrict__ edst,
               const unsigned short* __restrict__ bfr_all, // conv B [E][9][2][64][8]
               const float* __restrict__ bo_all,    // [E][27]
               const unsigned short* __restrict__ ws_all,  // samp B [E][9][NT][64][8]
               const float* __restrict__ bnS, const float* __restrict__ bnT,
               float* __restrict__ out)
{
    constexpr int NT = (COUT > 16) ? 2 : 1;
    const int b = blockIdx.y, e = blockIdx.z;
    const int ty0 = (blockIdx.x / 6) * 16, tx0 = (blockIdx.x % 6) * 16;
    const int tid = threadIdx.x;
    const int ly = tid >> 4, lx = tid & 15;
    const int h = ty0 + ly, w = tx0 + lx;
    const int r0 = ty0 - 2, c0 = tx0 - 2;            // staged box origin

    const float* __restrict__ xin = xin_all + (size_t)(e*BB + b)*CIN2*HWD;
    const float* __restrict__ bo  = bo_all + e*27;
    const unsigned short* __restrict__ bfr = bfr_all + (size_t)e*9216;
    const unsigned short* __restrict__ wsf = ws_all + (size_t)e*(9*NT*512);

    __shared__ unsigned short ldsb[3*GHALF];         // 20160 ushorts
    __shared__ unsigned short stile[256*SROW];       // 10240 ushorts (om / s-tile)

    // ---- stage bf16 tile: 3 groups x 420 pix x 8 ch ----
    #pragma unroll 1
    for (int i = tid; i < 3*NPIX; i += 256) {
        int g = i / NPIX;
        int pix = i - g*NPIX;
        int rr = pix / BCOL, cc = pix - rr*BCOL;
        int y = r0 + rr, x = c0 + cc;
        bool inb = (y >= 0 && y < HH && x >= 0 && x < WW);
        int hw = y*WW + x;
        unsigned int dpk[4];
        #pragma unroll
        for (int jj = 0; jj < 4; jj++) {
            unsigned int packed = 0;
            #pragma unroll
            for (int hl = 0; hl < 2; hl++) {
                int c = g*8 + jj*2 + hl;
                float v = 0.f;
                if (inb && c < CIN2) {
                    if (L1) {
                        int part = (c < NHID) ? esrc[e] : edst[e];
                        int ch   = (c < NHID) ? c : c - NHID;
                        v = xp[((size_t)(part*BB + b)*NHID + ch)*HWD + hw];
                    } else {
                        v = xin[(size_t)c*HWD + hw];
                        v = fmaxf(fmaf(v, bnS[e*CIN2 + c], bnT[e*CIN2 + c]), 0.f);
                    }
                }
                packed |= ((unsigned int)f2bfbits(v)) << (16*hl);
            }
            dpk[jj] = packed;
        }
        *reinterpret_cast<uint4*>(&ldsb[g*GHALF + pix*8]) =
            make_uint4(dpk[0], dpk[1], dpk[2], dpk[3]);
    }
    __syncthreads();

    const int lane = tid & 63;
    const int wv   = tid >> 6;
    const int lrow = lane & 15;
    const int lkg  = lane >> 4;

    // ---- offset conv via MFMA ----
    {
        const int gsel = (lkg < 3) ? lkg : 2;        // k>=24 lanes: B rows are 0
        f32x4 cacc[4][2];
        #pragma unroll
        for (int mt = 0; mt < 4; mt++)
            #pragma unroll
            for (int nt = 0; nt < 2; nt++)
                cacc[mt][nt] = f32x4{0.f, 0.f, 0.f, 0.f};

        const s16x8* ap = reinterpret_cast<const s16x8*>(&ldsb[gsel*GHALF]);
        #pragma unroll 1
        for (int t = 0; t < 9; t++) {
            const s16x8* bp = reinterpret_cast<const s16x8*>(bfr + t*1024);
            s16x8 b0 = bp[lane];
            s16x8 b1 = bp[64 + lane];
            int dty = t/3 - 1, dtx = t - (t/3)*3 - 1;
            #pragma unroll
            for (int mt = 0; mt < 4; mt++) {
                int pxl = wv*64 + mt*16 + lrow;
                int pix = ((pxl >> 4) + 2 + dty)*BCOL + ((pxl & 15) + 2 + dtx);
                s16x8 a = ap[pix];
                cacc[mt][0] = __builtin_amdgcn_mfma_f32_16x16x32_bf16(a, b0, cacc[mt][0], 0, 0, 0);
                cacc[mt][1] = __builtin_amdgcn_mfma_f32_16x16x32_bf16(a, b1, cacc[mt][1], 0, 0, 0);
            }
        }
        // write om tiles (C/D layout: col=lane&15, row=(lane>>4)*4+r)
        #pragma unroll
        for (int mt = 0; mt < 4; mt++)
            #pragma unroll
            for (int nt = 0; nt < 2; nt++)
                #pragma unroll
                for (int r = 0; r < 4; r++) {
                    int row = wv*64 + mt*16 + lkg*4 + r;
                    stile[row*SROW + nt*16 + lrow] = f2bfbits(cacc[mt][nt][r]);
                }
    }
    __syncthreads();

    // ---- unpack this pixel's om[27] (+bias); then zero cols 20..31 of row ----
    float om[27];
    {
        const uint4* orow = reinterpret_cast<const uint4*>(&stile[(size_t)tid*SROW]);
        uint4 u0 = orow[0], u1 = orow[1], u2 = orow[2], u3 = orow[3];
        unsigned int dwv[14] = {u0.x,u0.y,u0.z,u0.w, u1.x,u1.y,u1.z,u1.w,
                                u2.x,u2.y,u2.z,u2.w, u3.x,u3.y};
        #pragma unroll
        for (int o = 0; o < 27; o++) {
            unsigned int bits = (o & 1) ? (dwv[o>>1] >> 16) : (dwv[o>>1] & 0xffffu);
            om[o] = bfbits2f(bits) + bo[o];
        }
    }
    {
        unsigned short* mr = &stile[(size_t)tid*SROW];
        *reinterpret_cast<uint2*>(mr + 20) = make_uint2(0u, 0u);
        *reinterpret_cast<uint2*>(mr + 24) = make_uint2(0u, 0u);
        *reinterpret_cast<uint2*>(mr + 28) = make_uint2(0u, 0u);
    }

    // ---- sampling: per tap, scalar blend -> s-tile -> MFMA matvec ----
    f32x4 sacc[4][NT];
    #pragma unroll
    for (int mt = 0; mt < 4; mt++)
        #pragma unroll
        for (int nt = 0; nt < NT; nt++)
            sacc[mt][nt] = f32x4{0.f, 0.f, 0.f, 0.f};

    #pragma unroll
    for (int k = 0; k < 9; k++) {
        float m  = sigf(om[18 + k]);
        float ys = (float)(h + k/3 - 1) + om[2*k];
        float xs = (float)(w + k%3 - 1) + om[2*k + 1];
        float y0f = floorf(ys), x0f = floorf(xs);
        int iy = (int)y0f, ix = (int)x0f;
        float fy = ys - y0f, fx = xs - x0f;
        bool vy0 = (iy >= 0) && (iy < HH);
        bool vy1 = (iy >= -1) && (iy < HH-1);
        bool vx0 = (ix >= 0) && (ix < WW);
        bool vx1 = (ix >= -1) && (ix < WW-1);
        float w00 = (vy0 && vx0) ? (1.f-fy)*(1.f-fx)*m : 0.f;
        float w01 = (vy0 && vx1) ? (1.f-fy)*fx*m       : 0.f;
        float w10 = (vy1 && vx0) ? fy*(1.f-fx)*m       : 0.f;
        float w11 = (vy1 && vx1) ? fy*fx*m             : 0.f;
        int cy0 = min(max(iy,   0), HH-1), cy1 = min(max(iy+1, 0), HH-1);
        int cx0 = min(max(ix,   0), WW-1), cx1 = min(max(ix+1, 0), WW-1);

        unsigned int pk[10];
        bool staged = (cy0 >= r0) && (cy1 <= r0 + BOX-1) &&
                      (cx0 >= c0) && (cx1 <= c0 + BOX-1);
        if (staged) {
            const int p00 = (cy0-r0)*BCOL + (cx0-c0);
            const int p01 = (cy0-r0)*BCOL + (cx1-c0);
            const int p10 = (cy1-r0)*BCOL + (cx0-c0);
            const int p11 = (cy1-r0)*BCOL + (cx1-c0);
            #pragma unroll
            for (int g = 0; g < 3; g++) {
                const s16x8* gp = reinterpret_cast<const s16x8*>(&ldsb[g*GHALF]);
                s16x8 a8 = gp[p00], b8 = gp[p01], c8 = gp[p10], d8 = gp[p11];
                #pragma unroll
                for (int jp = 0; jp < 4; jp++) {
                    if (g*8 + jp*2 < CIN2) {
                        float s0, s1;
                        {
                            int j = jp*2;
                            float av = bfbits2f((unsigned short)a8[j]);
                            float bv = bfbits2f((unsigned short)b8[j]);
                            float cv = bfbits2f((unsigned short)c8[j]);
                            float dv = bfbits2f((unsigned short)d8[j]);
                            s0 = w00*av + w01*bv + w10*cv + w11*dv;
                        }
                        {
                            int j = jp*2 + 1;
                            float av = bfbits2f((unsigned short)a8[j]);
                            float bv = bfbits2f((unsigned short)b8[j]);
                            float cv = bfbits2f((unsigned short)c8[j]);
                            float dv = bfbits2f((unsigned short)d8[j]);
                            s1 = w00*av + w01*bv + w10*cv + w11*dv;
                        }
                        pk[g*4 + jp] = (unsigned int)f2bfbits(s0)
                                     | ((unsigned int)f2bfbits(s1) << 16);
                    }
                }
            }
        } else {
            int o00 = cy0*WW + cx0, o01 = cy0*WW + cx1;
            int o10 = cy1*WW + cx0, o11 = cy1*WW + cx1;
            float sv[20];
            #pragma unroll
            for (int c = 0; c < CIN2; c++) {
                const float* src;
                float sc = 1.f, sh = 0.f;
                if (L1) {
                    int part = (c < NHID) ? esrc[e] : edst[e];
                    int ch   = (c < NHID) ? c : c - NHID;
                    src = xp + ((size_t)(part*BB + b)*NHID + ch)*HWD;
                } else {
                    src = xin + (size_t)c*HWD;
                    sc = bnS[e*CIN2 + c]; sh = bnT[e*CIN2 + c];
                }
                float av = src[o00], bv = src[o01], cv = src[o10], dv = src[o11];
                if (!L1) {
                    av = fmaxf(fmaf(av, sc, sh), 0.f); bv = fmaxf(fmaf(bv, sc, sh), 0.f);
                    cv = fmaxf(fmaf(cv, sc, sh), 0.f); dv = fmaxf(fmaf(dv, sc, sh), 0.f);
                }
                sv[c] = w00*av + w01*bv + w10*cv + w11*dv;
            }
            #pragma unroll
            for (int jp = 0; jp < 10; jp++)
                pk[jp] = (unsigned int)f2bfbits(sv[2*jp])
                       | ((unsigned int)f2bfbits(sv[2*jp+1]) << 16);
        }

        {
            unsigned short* mr = &stile[(size_t)tid*SROW];
            *reinterpret_cast<uint4*>(mr)      = make_uint4(pk[0], pk[1], pk[2], pk[3]);
            *reinterpret_cast<uint4*>(mr + 8)  = make_uint4(pk[4], pk[5], pk[6], pk[7]);
            *reinterpret_cast<uint2*>(mr + 16) = make_uint2(pk[8], pk[9]);
        }
        __syncthreads();

        // MFMA: acc[pixel][o] += s[pixel][c] * Wd[c][o]  for this tap
        {
            const s16x8* wsp = reinterpret_cast<const s16x8*>(wsf + (size_t)k*NT*512);
            s16x8 wb0 = wsp[lane];
            s16x8 wb1{};
            if constexpr (NT == 2) wb1 = wsp[64 + lane];
            #pragma unroll
            for (int mt = 0; mt < 4; mt++) {
                int pxl = wv*64 + mt*16 + lrow;
                s16x8 a = *reinterpret_cast<const s16x8*>(&stile[pxl*SROW + lkg*8]);
                sacc[mt][0] = __builtin_amdgcn_mfma_f32_16x16x32_bf16(a, wb0, sacc[mt][0], 0, 0, 0);
                if constexpr (NT == 2)
                    sacc[mt][1] = __builtin_amdgcn_mfma_f32_16x16x32_bf16(a, wb1, sacc[mt][1], 0, 0, 0);
            }
        }
        if (k < 8) __syncthreads();
    }

    // ---- writeout (C/D layout scatter) ----
    float* op = out + (size_t)(e*BB + b)*COUT*HWD;
    #pragma unroll
    for (int mt = 0; mt < 4; mt++) {
        #pragma unroll
        for (int nt = 0; nt < NT; nt++) {
            int o = nt*16 + lrow;
            if (o < COUT) {
                #pragma unroll
                for (int r = 0; r < 4; r++) {
                    int p = wv*64 + mt*16 + lkg*4 + r;
                    op[(size_t)o*HWD + (ty0 + (p>>4))*WW + tx0 + (p&15)] = sacc[mt][nt][r];
                }
            }
        }
    }
}

// ---------------------------------------------------------------------------
// BN statistics (training mode, biased var, eps=1e-5), folding gamma/beta.
// ---------------------------------------------------------------------------
__device__ __forceinline__ void bn_finish(float s1, float s2, int n, float g, float bt,
                                          float* scale, float* shift, int idx)
{
    float mean = s1 / (float)n;
    float var  = fmaxf(s2 / (float)n - mean*mean, 0.f);
    float rs   = rsqrtf(var + 1e-5f);
    scale[idx] = g * rs;
    shift[idx] = bt - mean * g * rs;
}

template<int C>
__global__ __launch_bounds__(256)
void bn_stats_flat(const float* __restrict__ x, const float* __restrict__ gamma,
                   const float* __restrict__ beta, float* __restrict__ scale,
                   float* __restrict__ shift)
{
    const int gc = blockIdx.x;
    const int g = gc / C, c = gc % C;
    const int N = BB * HWD;
    float s1 = 0.f, s2 = 0.f;
    for (int idx = threadIdx.x; idx < N; idx += 256) {
        int b = idx / HWD, p = idx % HWD;
        float v = x[((size_t)(g*BB + b)*C + c)*HWD + p];
        s1 += v; s2 += v*v;
    }
    __shared__ float r1[256], r2[256];
    r1[threadIdx.x] = s1; r2[threadIdx.x] = s2;
    __syncthreads();
    for (int s = 128; s > 0; s >>= 1) {
        if (threadIdx.x < s) { r1[threadIdx.x] += r1[threadIdx.x+s]; r2[threadIdx.x] += r2[threadIdx.x+s]; }
        __syncthreads();
    }
    if (threadIdx.x == 0)
        bn_finish(r1[0], r2[0], N, gamma[gc], beta[gc], scale, shift, gc);
}

// ---------------------------------------------------------------------------
// Fused msg + gate + q (scalar, MLP via 8-batched loads).  grid: (36, B, P)
// ---------------------------------------------------------------------------
__global__ __launch_bounds__(256)
void mgq_kernel(const float* __restrict__ t2all, const float* __restrict__ s2,
                const float* __restrict__ sh2, const float* __restrict__ o_w,
                const float* __restrict__ o_b, const float* __restrict__ a_w,
                const float* __restrict__ a_b, const float* __restrict__ xp,
                const float* __restrict__ xh,
                const float* __restrict__ att_w, const float* __restrict__ att_b,
                const float* __restrict__ du_w, const float* __restrict__ du_b,
                const float* __restrict__ dl_w, const float* __restrict__ dl_b,
                const int* __restrict__ esrc, const int* __restrict__ edst,
                const float* __restrict__ p_fea, const float* __restrict__ wq_all,
                float* __restrict__ y)
{
    int px = blockIdx.x * 256 + threadIdx.x;
    int b = blockIdx.y, p = blockIdx.z;

    float s = att_b[p];
    #pragma unroll
    for (int c = 0; c < NHID; c++)
        s += xp[((size_t)(p*BB + b)*NHID + c)*HWD + px] * att_w[p*NHID + c];
    float satt = sigf(s);

    int hs = (p < 4) ? 0 : 1;
    const float* dw = (p < 4) ? du_w : dl_w;
    float d = (p < 4) ? du_b[0] : dl_b[0];
    #pragma unroll
    for (int c = 0; c < NHID; c++)
        d += xh[((size_t)(hs*BB + b)*NHID + c)*HWD + px] * dw[c];
    float dec = sigf(d);

    float xpp = 0.f;
    for (int e = 0; e < NE; e++) {
        if (edst[e] != p) continue;
        float sab = o_b[e];
        #pragma unroll
        for (int c = 0; c < NHID; c++) {
            float v = t2all[((size_t)(e*BB + b)*NHID + c)*HWD + px];
            v = fmaxf(fmaf(v, s2[e*NHID+c], sh2[e*NHID+c]), 0.f);
            sab += v * o_w[e*NHID + c];
        }
        int sp = esrc[e];
        float sa = a_b[e];
        #pragma unroll
        for (int c = 0; c < NHID; c++)
            sa += xp[((size_t)(sp*BB + b)*NHID + c)*HWD + px] * a_w[e*NHID + c];
        xpp += sigf(sab) * (1.f - sigf(sa));
    }
    float gate = 1.f + dec + satt + xpp;

    const float* wq = wq_all + (size_t)p*NIN*NHID;
    const float* pf = p_fea + (size_t)b*NIN*HWD + px;
    float acc[NHID];
    #pragma unroll
    for (int o = 0; o < NHID; o++) acc[o] = 0.f;
    for (int c = 0; c < NIN; c += 8) {
        float v0 = pf[(size_t)(c+0)*HWD];
        float v1 = pf[(size_t)(c+1)*HWD];
        float v2 = pf[(size_t)(c+2)*HWD];
        float v3 = pf[(size_t)(c+3)*HWD];
        float v4 = pf[(size_t)(c+4)*HWD];
        float v5 = pf[(size_t)(c+5)*HWD];
        float v6 = pf[(size_t)(c+6)*HWD];
        float v7 = pf[(size_t)(c+7)*HWD];
        const float* wc = wq + c*NHID;
        #pragma unroll
        for (int o = 0; o < NHID; o++) acc[o] = fmaf(v0, wc[o], acc[o]);
        #pragma unroll
        for (int o = 0; o < NHID; o++) acc[o] = fmaf(v1, wc[NHID + o], acc[o]);
        #pragma unroll
        for (int o = 0; o < NHID; o++) acc[o] = fmaf(v2, wc[2*NHID + o], acc[o]);
        #pragma unroll
        for (int o = 0; o < NHID; o++) acc[o] = fmaf(v3, wc[3*NHID + o], acc[o]);
        #pragma unroll
        for (int o = 0; o < NHID; o++) acc[o] = fmaf(v4, wc[4*NHID + o], acc[o]);
        #pragma unroll
        for (int o = 0; o < NHID; o++) acc[o] = fmaf(v5, wc[5*NHID + o], acc[o]);
        #pragma unroll
        for (int o = 0; o < NHID; o++) acc[o] = fmaf(v6, wc[6*NHID + o], acc[o]);
        #pragma unroll
        for (int o = 0; o < NHID; o++) acc[o] = fmaf(v7, wc[7*NHID + o], acc[o]);
    }
    float* yp = y + ((size_t)(p*BB + b)*NHID)*HWD + px;
    #pragma unroll
    for (int o = 0; o < NHID; o++) yp[(size_t)o*HWD] = acc[o] * gate;
}

// ---------------------------------------------------------------------------
// out = relu(bn5(y));   grid: (36, B*HID, P)
// ---------------------------------------------------------------------------
__global__ __launch_bounds__(256)
void out_kernel(const float* __restrict__ y, const float* __restrict__ s5,
                const float* __restrict__ t5, float* __restrict__ out)
{
    int px = blockIdx.x * 256 + threadIdx.x;
    int bo = blockIdx.y, p = blockIdx.z;
    int b = bo / NHID, o = bo % NHID;
    size_t idx = ((size_t)(p*BB + b)*NHID + o)*HWD + px;
    out[idx] = fmaxf(fmaf(y[idx], s5[p*NHID+o], t5[p*NHID+o]), 0.f);
}

// ---------------------------------------------------------------------------
// launcher
// ---------------------------------------------------------------------------
extern "C" void kernel_launch(void* const* d_in, const int* in_sizes, int n_in,
                              void* d_out, int out_size, void* d_ws, size_t ws_size,
                              hipStream_t stream)
{
    (void)in_sizes; (void)n_in; (void)out_size; (void)ws_size;

    const float* p_fea  = (const float*)d_in[0];
    const float* xp     = (const float*)d_in[1];
    const float* xh     = (const float*)d_in[2];
    const float* att_w  = (const float*)d_in[3];
    const float* att_b  = (const float*)d_in[4];
    const float* du_w   = (const float*)d_in[5];
    const float* du_b   = (const float*)d_in[6];
    const float* dl_w   = (const float*)d_in[7];
    const float* dl_b   = (const float*)d_in[8];
    const float* upd_w  = (const float*)d_in[9];
    const float* upd_g  = (const float*)d_in[10];
    const float* upd_b  = (const float*)d_in[11];
    const float* off1_w = (const float*)d_in[12];
    const float* off1_b = (const float*)d_in[13];
    const float* dcn1_w = (const float*)d_in[14];
    const float* bn1_g  = (const float*)d_in[15];
    const float* bn1_b  = (const float*)d_in[16];
    const float* off2_w = (const float*)d_in[17];
    const float* off2_b = (const float*)d_in[18];
    const float* dcn2_w = (const float*)d_in[19];
    const float* bn2_g  = (const float*)d_in[20];
    const float* bn2_b  = (const float*)d_in[21];
    const float* out_w  = (const float*)d_in[22];
    const float* out_b  = (const float*)d_in[23];
    const float* aatt_w = (const float*)d_in[24];
    const float* aatt_b = (const float*)d_in[25];
    const int* esrc     = (const int*)d_in[26];
    const int* edst     = (const int*)d_in[27];
    float* outp = (float*)d_out;
    float* ws = (float*)d_ws;

    // workspace layout (float offsets; ushort arrays occupy half-floats)
    constexpr size_t o_x1   = 0;                                    // [E][B][20][HWD]
    constexpr size_t o_t2   = o_x1  + (size_t)NE*BB*CIN2*HWD;       // [E][B][10][HWD]
    constexpr size_t o_bf1  = o_t2  + (size_t)NE*BB*NHID*HWD;       // 110592 ush
    constexpr size_t o_b1   = o_bf1 + 55296;
    constexpr size_t o_ws1  = o_b1  + 324;                          // 110592 ush
    constexpr size_t o_bf2  = o_ws1 + 55296;                        // 110592 ush
    constexpr size_t o_b2   = o_bf2 + 55296;
    constexpr size_t o_ws2  = o_b2  + 324;                          // 55296 ush
    constexpr size_t o_uw   = o_ws2 + 27648;
    constexpr size_t o_bn1s = o_uw  + 15360;
    constexpr size_t o_bn1t = o_bn1s + NE*CIN2;
    constexpr size_t o_bn2s = o_bn1t + NE*CIN2;
    constexpr size_t o_bn2t = o_bn2s + NE*NHID;
    constexpr size_t o_bn5s = o_bn2t + NE*NHID;
    constexpr size_t o_bn5t = o_bn5s + NPART*NHID;
    constexpr size_t o_y    = o_bn5t + NPART*NHID;                  // [P][B][10][HWD]
    float* x1 = ws + o_x1;
    float* t2 = ws + o_t2;
    float* y  = ws + o_y;
    unsigned short* bf1 = (unsigned short*)(ws + o_bf1);
    unsigned short* ws1 = (unsigned short*)(ws + o_ws1);
    unsigned short* bf2 = (unsigned short*)(ws + o_bf2);
    unsigned short* ws2 = (unsigned short*)(ws + o_ws2);

    // items: 110592+324+110592+110592+324+55296+15360 = 403080 -> 1575 blocks
    xpose_weights<<<dim3(1575), 256, 0, stream>>>(
        off1_w, off1_b, dcn1_w, off2_w, off2_b, dcn2_w, upd_w,
        bf1, ws+o_b1, ws1, bf2, ws+o_b2, ws2, ws+o_uw);

    dcn_tiled<CIN2, true><<<dim3(36, BB, NE), 256, 0, stream>>>(
        nullptr, xp, esrc, edst, bf1, ws+o_b1, ws1,
        nullptr, nullptr, x1);

    bn_stats_flat<CIN2><<<dim3(NE*CIN2), 256, 0, stream>>>(
        x1, bn1_g, bn1_b, ws+o_bn1s, ws+o_bn1t);

    dcn_tiled<NHID, false><<<dim3(36, BB, NE), 256, 0, stream>>>(
        x1, nullptr, esrc, edst, bf2, ws+o_b2, ws2,
        ws+o_bn1s, ws+o_bn1t, t2);

    bn_stats_flat<NHID><<<dim3(NE*NHID), 256, 0, stream>>>(
        t2, bn2_g, bn2_b, ws+o_bn2s, ws+o_bn2t);

    mgq_kernel<<<dim3(36, BB, NPART), 256, 0, stream>>>(
        t2, ws+o_bn2s, ws+o_bn2t, out_w, out_b, aatt_w, aatt_b, xp, xh,
        att_w, att_b, du_w, du_b, dl_w, dl_b, esrc, edst,
        p_fea, ws+o_uw, y);

    bn_stats_flat<NHID><<<dim3(NPART*NHID), 256, 0, stream>>>(
        y, upd_g, upd_b, ws+o_bn5s, ws+o_bn5t);

    out_kernel<<<dim3(36, BB*NHID, NPART), 256, 0, stream>>>(
        y, ws+o_bn5s, ws+o_bn5t, outp);
}

// Round 15
// 191.174 us; speedup vs baseline: 2.4621x; 1.0036x over previous
//
#include <hip/hip_runtime.h>
#include <hip/hip_bf16.h>

// ---------------------------------------------------------------------------
// Part_Graph: deformable-conv message passing over a 6-node part graph.
// B=2, H=W=96, IN=256, HID=10, P=6, E=12, K=9 taps.  ALL I/O is float32.
// dcn: offset-conv AND sampling tap-matvec via bf16 MFMA (16x16x32).
// After the one staging barrier, ALL LDS traffic is wave-private (incl. the
// writeout bounce, wave-quartered) -> block barriers replaced by intra-wave
// lgkmcnt fences.
// ---------------------------------------------------------------------------

#define NE 12
#define NPART 6
#define BB 2
#define HH 96
#define WW 96
#define HWD (HH*WW)          // 9216
#define CIN2 20              // 2*HID concat channels
#define NHID 10
#define NIN 256

// LDS tile geometry: 16x16 output tile, +-2 halo -> 20x20 box.
#define BOX 20
#define BCOL 21              // pix = rr*BCOL + cc
#define NPIX (BOX*BCOL)      // 420
#define GHALF (NPIX*8)       // ushorts per 8-channel group = 3360
#define SROW 40              // s-tile row stride (ushorts): 80 B, 16B-aligned

typedef __attribute__((ext_vector_type(8))) short s16x8;
typedef __attribute__((ext_vector_type(4))) float f32x4;

__device__ __forceinline__ float sigf(float x) { return 1.f / (1.f + __expf(-x)); }
__device__ __forceinline__ float bfbits2f(unsigned int u) {
    return __uint_as_float(u << 16);
}
__device__ __forceinline__ unsigned short f2bfbits(float v) {
    __hip_bfloat16 h = __float2bfloat16(v);
    return *reinterpret_cast<unsigned short*>(&h);
}
// Intra-wave LDS fence: drain this wave's DS ops; sched_barrier stops hipcc
// hoisting dependent ops above the wait (guide rule #18).
__device__ __forceinline__ void wave_lds_fence() {
    asm volatile("s_waitcnt lgkmcnt(0)" ::: "memory");
    __builtin_amdgcn_sched_barrier(0);
}

// ---------------------------------------------------------------------------
// Weight prep (bf16 MFMA B-fragments + fp32 bias + fp32 upd):
//   bf*  : [e][t=9][nt=2][lane=64][i=8]  conv weights
//          value = Woff[k=(lane>>4)*8+i][col=nt*16+(lane&15)]  (zero-padded)
//   ws1  : [e][t=9][nt=2][lane=64][i=8]  sampling weights L1 (COUT=20)
//   ws2  : [e][t=9][nt=1][lane=64][i=8]  sampling weights L2 (COUT=10)
//          value = Wd[c=(lane>>4)*8+i][o=nt*16+(lane&15)]      (zero-padded)
//   b*   : [e][27] fp32 conv bias;  uwt: [p][c=256][o=10] fp32
// ---------------------------------------------------------------------------
__global__ __launch_bounds__(256)
void xpose_weights(const float* __restrict__ off1_w, const float* __restrict__ off1_b,
                   const float* __restrict__ dcn1_w,
                   const float* __restrict__ off2_w, const float* __restrict__ off2_b,
                   const float* __restrict__ dcn2_w,
                   const float* __restrict__ upd_w,
                   unsigned short* __restrict__ bf1, float* __restrict__ o1b,
                   unsigned short* __restrict__ ws1,
                   unsigned short* __restrict__ bf2, float* __restrict__ o2b,
                   unsigned short* __restrict__ ws2,
                   float* __restrict__ uwt)
{
    int idx = blockIdx.x * 256 + threadIdx.x;
    if (idx < 110592) {                      // bf1 [e][t][nt][lane][i]
        int e = idx / 9216, r = idx % 9216;
        int t = r / 1024, r2 = r % 1024;
        int nt = r2 / 512, r3 = r2 % 512;
        int lane = r3 / 8, i = r3 % 8;
        int k = (lane >> 4)*8 + i;
        int col = nt*16 + (lane & 15);
        float v = (k < CIN2 && col < 27) ? off1_w[((e*27 + col)*CIN2 + k)*9 + t] : 0.f;
        bf1[idx] = f2bfbits(v);
        return;
    }
    idx -= 110592;
    if (idx < 324) { o1b[idx] = off1_b[idx]; return; }
    idx -= 324;
    if (idx < 110592) {                      // ws1 [e][t][nt][lane][i]  (COUT=20)
        int e = idx / 9216, r = idx % 9216;
        int t = r / 1024, r2 = r % 1024;
        int nt = r2 / 512, r3 = r2 % 512;
        int lane = r3 / 8, i = r3 % 8;
        int c = (lane >> 4)*8 + i;
        int o = nt*16 + (lane & 15);
        float v = (c < CIN2 && o < CIN2) ? dcn1_w[((e*20 + o)*CIN2 + c)*9 + t] : 0.f;
        ws1[idx] = f2bfbits(v);
        return;
    }
    idx -= 110592;
    if (idx < 110592) {                      // bf2
        int e = idx / 9216, r = idx % 9216;
        int t = r / 1024, r2 = r % 1024;
        int nt = r2 / 512, r3 = r2 % 512;
        int lane = r3 / 8, i = r3 % 8;
        int k = (lane >> 4)*8 + i;
        int col = nt*16 + (lane & 15);
        float v = (k < CIN2 && col < 27) ? off2_w[((e*27 + col)*CIN2 + k)*9 + t] : 0.f;
        bf2[idx] = f2bfbits(v);
        return;
    }
    idx -= 110592;
    if (idx < 324) { o2b[idx] = off2_b[idx]; return; }
    idx -= 324;
    if (idx < 55296) {                       // ws2 [e][t][1][lane][i]  (COUT=10)
        int e = idx / 4608, r = idx % 4608;
        int t = r / 512, r3 = r % 512;
        int lane = r3 / 8, i = r3 % 8;
        int c = (lane >> 4)*8 + i;
        int o = lane & 15;
        float v = (c < CIN2 && o < NHID) ? dcn2_w[((e*10 + o)*CIN2 + c)*9 + t] : 0.f;
        ws2[idx] = f2bfbits(v);
        return;
    }
    idx -= 55296;
    if (idx < 15360) {                       // upd_wt [p][c][10]
        int p = idx / 2560, r = idx % 2560, c = r / 10, o = r % 10;
        uwt[idx] = upd_w[(p*10 + o)*256 + c];
        return;
    }
}

// ---------------------------------------------------------------------------
// Fused DCNv2 layer: MFMA offset-conv + MFMA sampling matvec, wave-async.
// 256 threads = 4 waves; LDS: ldsb 20.2 KB (bf16 tile, read-only after one
// barrier) + stile 20.5 KB (wave-private rows: om buf, s-tiles, out bounce
// in wave-quartered 5 KB regions).
// grid: (36, B, E)
// ---------------------------------------------------------------------------
template<int COUT, bool L1>
__global__ __launch_bounds__(256, 4)
void dcn_tiled(const float* __restrict__ xin_all,
               const float* __restrict__ xp,        // only for L1 gather
               const int* __restrict__ esrc, const int* __restrict__ edst,
               const unsigned short* __restrict__ bfr_all, // conv B [E][9][2][64][8]
               const float* __restrict__ bo_all,    // [E][27]
               const unsigned short* __restrict__ ws_all,  // samp B [E][9][NT][64][8]
               const float* __restrict__ bnS, const float* __restrict__ bnT,
               float* __restrict__ out)
{
    constexpr int NT = (COUT > 16) ? 2 : 1;
    const int b = blockIdx.y, e = blockIdx.z;
    const int ty0 = (blockIdx.x / 6) * 16, tx0 = (blockIdx.x % 6) * 16;
    const int tid = threadIdx.x;
    const int ly = tid >> 4, lx = tid & 15;
    const int h = ty0 + ly, w = tx0 + lx;
    const int r0 = ty0 - 2, c0 = tx0 - 2;            // staged box origin

    const float* __restrict__ xin = xin_all + (size_t)(e*BB + b)*CIN2*HWD;
    const float* __restrict__ bo  = bo_all + e*27;
    const unsigned short* __restrict__ bfr = bfr_all + (size_t)e*9216;
    const unsigned short* __restrict__ wsf = ws_all + (size_t)e*(9*NT*512);

    __shared__ unsigned short ldsb[3*GHALF];         // 20160 ushorts
    __shared__ unsigned short stile[256*SROW];       // 10240 ushorts = 20480 B

    // ---- stage bf16 tile: 3 groups x 420 pix x 8 ch ----
    #pragma unroll 1
    for (int i = tid; i < 3*NPIX; i += 256) {
        int g = i / NPIX;
        int pix = i - g*NPIX;
        int rr = pix / BCOL, cc = pix - rr*BCOL;
        int y = r0 + rr, x = c0 + cc;
        bool inb = (y >= 0 && y < HH && x >= 0 && x < WW);
        int hw = y*WW + x;
        unsigned int dpk[4];
        #pragma unroll
        for (int jj = 0; jj < 4; jj++) {
            unsigned int packed = 0;
            #pragma unroll
            for (int hl = 0; hl < 2; hl++) {
                int c = g*8 + jj*2 + hl;
                float v = 0.f;
                if (inb && c < CIN2) {
                    if (L1) {
                        int part = (c < NHID) ? esrc[e] : edst[e];
                        int ch   = (c < NHID) ? c : c - NHID;
                        v = xp[((size_t)(part*BB + b)*NHID + ch)*HWD + hw];
                    } else {
                        v = xin[(size_t)c*HWD + hw];
                        v = fmaxf(fmaf(v, bnS[e*CIN2 + c], bnT[e*CIN2 + c]), 0.f);
                    }
                }
                packed |= ((unsigned int)f2bfbits(v)) << (16*hl);
            }
            dpk[jj] = packed;
        }
        *reinterpret_cast<uint4*>(&ldsb[g*GHALF + pix*8]) =
            make_uint4(dpk[0], dpk[1], dpk[2], dpk[3]);
    }
    __syncthreads();     // the ONLY block-wide barrier (ldsb is cross-wave)

    const int lane = tid & 63;
    const int wv   = tid >> 6;
    const int lrow = lane & 15;
    const int lkg  = lane >> 4;

    // ---- offset conv via MFMA ----
    {
        const int gsel = (lkg < 3) ? lkg : 2;        // k>=24 lanes: B rows are 0
        f32x4 cacc[4][2];
        #pragma unroll
        for (int mt = 0; mt < 4; mt++)
            #pragma unroll
            for (int nt = 0; nt < 2; nt++)
                cacc[mt][nt] = f32x4{0.f, 0.f, 0.f, 0.f};

        const s16x8* ap = reinterpret_cast<const s16x8*>(&ldsb[gsel*GHALF]);
        #pragma unroll 1
        for (int t = 0; t < 9; t++) {
            const s16x8* bp = reinterpret_cast<const s16x8*>(bfr + t*1024);
            s16x8 b0 = bp[lane];
            s16x8 b1 = bp[64 + lane];
            int dty = t/3 - 1, dtx = t - (t/3)*3 - 1;
            #pragma unroll
            for (int mt = 0; mt < 4; mt++) {
                int pxl = wv*64 + mt*16 + lrow;
                int pix = ((pxl >> 4) + 2 + dty)*BCOL + ((pxl & 15) + 2 + dtx);
                s16x8 a = ap[pix];
                cacc[mt][0] = __builtin_amdgcn_mfma_f32_16x16x32_bf16(a, b0, cacc[mt][0], 0, 0, 0);
                cacc[mt][1] = __builtin_amdgcn_mfma_f32_16x16x32_bf16(a, b1, cacc[mt][1], 0, 0, 0);
            }
        }
        // write om tiles (C/D layout: col=lane&15, row=(lane>>4)*4+r)
        // rows wv*64..wv*64+63: wave-private.
        #pragma unroll
        for (int mt = 0; mt < 4; mt++)
            #pragma unroll
            for (int nt = 0; nt < 2; nt++)
                #pragma unroll
                for (int r = 0; r < 4; r++) {
                    int row = wv*64 + mt*16 + lkg*4 + r;
                    stile[row*SROW + nt*16 + lrow] = f2bfbits(cacc[mt][nt][r]);
                }
    }
    wave_lds_fence();

    // ---- unpack this pixel's om[27] (+bias); then zero cols 20..31 of row ----
    float om[27];
    {
        const uint4* orow = reinterpret_cast<const uint4*>(&stile[(size_t)tid*SROW]);
        uint4 u0 = orow[0], u1 = orow[1], u2 = orow[2], u3 = orow[3];
        unsigned int dwv[14] = {u0.x,u0.y,u0.z,u0.w, u1.x,u1.y,u1.z,u1.w,
                                u2.x,u2.y,u2.z,u2.w, u3.x,u3.y};
        #pragma unroll
        for (int o = 0; o < 27; o++) {
            unsigned int bits = (o & 1) ? (dwv[o>>1] >> 16) : (dwv[o>>1] & 0xffffu);
            om[o] = bfbits2f(bits) + bo[o];
        }
    }
    {
        unsigned short* mr = &stile[(size_t)tid*SROW];
        *reinterpret_cast<uint2*>(mr + 20) = make_uint2(0u, 0u);
        *reinterpret_cast<uint2*>(mr + 24) = make_uint2(0u, 0u);
        *reinterpret_cast<uint2*>(mr + 28) = make_uint2(0u, 0u);
    }

    // ---- sampling: per tap, scalar blend -> s-row -> wave fence -> MFMA ----
    f32x4 sacc[4][NT];
    #pragma unroll
    for (int mt = 0; mt < 4; mt++)
        #pragma unroll
        for (int nt = 0; nt < NT; nt++)
            sacc[mt][nt] = f32x4{0.f, 0.f, 0.f, 0.f};

    #pragma unroll
    for (int k = 0; k < 9; k++) {
        float m  = sigf(om[18 + k]);
        float ys = (float)(h + k/3 - 1) + om[2*k];
        float xs = (float)(w + k%3 - 1) + om[2*k + 1];
        float y0f = floorf(ys), x0f = floorf(xs);
        int iy = (int)y0f, ix = (int)x0f;
        float fy = ys - y0f, fx = xs - x0f;
        bool vy0 = (iy >= 0) && (iy < HH);
        bool vy1 = (iy >= -1) && (iy < HH-1);
        bool vx0 = (ix >= 0) && (ix < WW);
        bool vx1 = (ix >= -1) && (ix < WW-1);
        float w00 = (vy0 && vx0) ? (1.f-fy)*(1.f-fx)*m : 0.f;
        float w01 = (vy0 && vx1) ? (1.f-fy)*fx*m       : 0.f;
        float w10 = (vy1 && vx0) ? fy*(1.f-fx)*m       : 0.f;
        float w11 = (vy1 && vx1) ? fy*fx*m             : 0.f;
        int cy0 = min(max(iy,   0), HH-1), cy1 = min(max(iy+1, 0), HH-1);
        int cx0 = min(max(ix,   0), WW-1), cx1 = min(max(ix+1, 0), WW-1);

        unsigned int pk[10];
        bool staged = (cy0 >= r0) && (cy1 <= r0 + BOX-1) &&
                      (cx0 >= c0) && (cx1 <= c0 + BOX-1);
        if (staged) {
            const int p00 = (cy0-r0)*BCOL + (cx0-c0);
            const int p01 = (cy0-r0)*BCOL + (cx1-c0);
            const int p10 = (cy1-r0)*BCOL + (cx0-c0);
            const int p11 = (cy1-r0)*BCOL + (cx1-c0);
            #pragma unroll
            for (int g = 0; g < 3; g++) {
                const s16x8* gp = reinterpret_cast<const s16x8*>(&ldsb[g*GHALF]);
                s16x8 a8 = gp[p00], b8 = gp[p01], c8 = gp[p10], d8 = gp[p11];
                #pragma unroll
                for (int jp = 0; jp < 4; jp++) {
                    if (g*8 + jp*2 < CIN2) {
                        float s0, s1;
                        {
                            int j = jp*2;
                            float av = bfbits2f((unsigned short)a8[j]);
                            float bv = bfbits2f((unsigned short)b8[j]);
                            float cv = bfbits2f((unsigned short)c8[j]);
                            float dv = bfbits2f((unsigned short)d8[j]);
                            s0 = w00*av + w01*bv + w10*cv + w11*dv;
                        }
                        {
                            int j = jp*2 + 1;
                            float av = bfbits2f((unsigned short)a8[j]);
                            float bv = bfbits2f((unsigned short)b8[j]);
                            float cv = bfbits2f((unsigned short)c8[j]);
                            float dv = bfbits2f((unsigned short)d8[j]);
                            s1 = w00*av + w01*bv + w10*cv + w11*dv;
                        }
                        pk[g*4 + jp] = (unsigned int)f2bfbits(s0)
                                     | ((unsigned int)f2bfbits(s1) << 16);
                    }
                }
            }
        } else {
            int o00 = cy0*WW + cx0, o01 = cy0*WW + cx1;
            int o10 = cy1*WW + cx0, o11 = cy1*WW + cx1;
            float sv[20];
            #pragma unroll
            for (int c = 0; c < CIN2; c++) {
                const float* src;
                float sc = 1.f, sh = 0.f;
                if (L1) {
                    int part = (c < NHID) ? esrc[e] : edst[e];
                    int ch   = (c < NHID) ? c : c - NHID;
                    src = xp + ((size_t)(part*BB + b)*NHID + ch)*HWD;
                } else {
                    src = xin + (size_t)c*HWD;
                    sc = bnS[e*CIN2 + c]; sh = bnT[e*CIN2 + c];
                }
                float av = src[o00], bv = src[o01], cv = src[o10], dv = src[o11];
                if (!L1) {
                    av = fmaxf(fmaf(av, sc, sh), 0.f); bv = fmaxf(fmaf(bv, sc, sh), 0.f);
                    cv = fmaxf(fmaf(cv, sc, sh), 0.f); dv = fmaxf(fmaf(dv, sc, sh), 0.f);
                }
                sv[c] = w00*av + w01*bv + w10*cv + w11*dv;
            }
            #pragma unroll
            for (int jp = 0; jp < 10; jp++)
                pk[jp] = (unsigned int)f2bfbits(sv[2*jp])
                       | ((unsigned int)f2bfbits(sv[2*jp+1]) << 16);
        }

        {   // write own s-row (wave-private)
            unsigned short* mr = &stile[(size_t)tid*SROW];
            *reinterpret_cast<uint4*>(mr)      = make_uint4(pk[0], pk[1], pk[2], pk[3]);
            *reinterpret_cast<uint4*>(mr + 8)  = make_uint4(pk[4], pk[5], pk[6], pk[7]);
            *reinterpret_cast<uint2*>(mr + 16) = make_uint2(pk[8], pk[9]);
        }
        wave_lds_fence();

        // MFMA: acc[pixel][o] += s[pixel][c] * Wd[c][o]  (reads wave-own rows)
        {
            const s16x8* wsp = reinterpret_cast<const s16x8*>(wsf + (size_t)k*NT*512);
            s16x8 wb0 = wsp[lane];
            s16x8 wb1{};
            if constexpr (NT == 2) wb1 = wsp[64 + lane];
            #pragma unroll
            for (int mt = 0; mt < 4; mt++) {
                int pxl = wv*64 + mt*16 + lrow;
                s16x8 a = *reinterpret_cast<const s16x8*>(&stile[pxl*SROW + lkg*8]);
                sacc[mt][0] = __builtin_amdgcn_mfma_f32_16x16x32_bf16(a, wb0, sacc[mt][0], 0, 0, 0);
                if constexpr (NT == 2)
                    sacc[mt][1] = __builtin_amdgcn_mfma_f32_16x16x32_bf16(a, wb1, sacc[mt][1], 0, 0, 0);
            }
        }
        wave_lds_fence();   // A-reads drained before next tap's s-row write
    }

    // ---- writeout: wave-quartered LDS bounce (5 KB/wave = own dead s-rows),
    //      then coalesced global stores. NO cross-wave bytes touched. ----
    {
        float* ldsf = reinterpret_cast<float*>(stile) + wv*1280;  // 5120 B/wave
        #pragma unroll
        for (int mt = 0; mt < 4; mt++) {
            #pragma unroll
            for (int nt = 0; nt < NT; nt++) {
                int o = nt*16 + lrow;
                if (o < COUT) {
                    #pragma unroll
                    for (int r = 0; r < 4; r++) {
                        int lp = mt*16 + lkg*4 + r;          // 0..63 in-wave pixel
                        ldsf[o*64 + lp] = sacc[mt][nt][r];
                    }
                }
            }
        }
        wave_lds_fence();
        float* op = out + (size_t)(e*BB + b)*COUT*HWD + h*WW + w;
        #pragma unroll
        for (int o = 0; o < COUT; o++)
            op[(size_t)o*HWD] = ldsf[o*64 + (tid & 63)];
    }
}

// ---------------------------------------------------------------------------
// BN statistics (training mode, biased var, eps=1e-5), folding gamma/beta.
// ---------------------------------------------------------------------------
__device__ __forceinline__ void bn_finish(float s1, float s2, int n, float g, float bt,
                                          float* scale, float* shift, int idx)
{
    float mean = s1 / (float)n;
    float var  = fmaxf(s2 / (float)n - mean*mean, 0.f);
    float rs   = rsqrtf(var + 1e-5f);
    scale[idx] = g * rs;
    shift[idx] = bt - mean * g * rs;
}

template<int C>
__global__ __launch_bounds__(256)
void bn_stats_flat(const float* __restrict__ x, const float* __restrict__ gamma,
                   const float* __restrict__ beta, float* __restrict__ scale,
                   float* __restrict__ shift)
{
    const int gc = blockIdx.x;
    const int g = gc / C, c = gc % C;
    const int N = BB * HWD;
    float s1 = 0.f, s2 = 0.f;
    for (int idx = threadIdx.x; idx < N; idx += 256) {
        int b = idx / HWD, p = idx % HWD;
        float v = x[((size_t)(g*BB + b)*C + c)*HWD + p];
        s1 += v; s2 += v*v;
    }
    __shared__ float r1[256], r2[256];
    r1[threadIdx.x] = s1; r2[threadIdx.x] = s2;
    __syncthreads();
    for (int s = 128; s > 0; s >>= 1) {
        if (threadIdx.x < s) { r1[threadIdx.x] += r1[threadIdx.x+s]; r2[threadIdx.x] += r2[threadIdx.x+s]; }
        __syncthreads();
    }
    if (threadIdx.x == 0)
        bn_finish(r1[0], r2[0], N, gamma[gc], beta[gc], scale, shift, gc);
}

// ---------------------------------------------------------------------------
// Fused msg + gate + q (scalar, MLP via 8-batched loads).  grid: (36, B, P)
// ---------------------------------------------------------------------------
__global__ __launch_bounds__(256)
void mgq_kernel(const float* __restrict__ t2all, const float* __restrict__ s2,
                const float* __restrict__ sh2, const float* __restrict__ o_w,
                const float* __restrict__ o_b, const float* __restrict__ a_w,
                const float* __restrict__ a_b, const float* __restrict__ xp,
                const float* __restrict__ xh,
                const float* __restrict__ att_w, const float* __restrict__ att_b,
                const float* __restrict__ du_w, const float* __restrict__ du_b,
                const float* __restrict__ dl_w, const float* __restrict__ dl_b,
                const int* __restrict__ esrc, const int* __restrict__ edst,
                const float* __restrict__ p_fea, const float* __restrict__ wq_all,
                float* __restrict__ y)
{
    int px = blockIdx.x * 256 + threadIdx.x;
    int b = blockIdx.y, p = blockIdx.z;

    float s = att_b[p];
    #pragma unroll
    for (int c = 0; c < NHID; c++)
        s += xp[((size_t)(p*BB + b)*NHID + c)*HWD + px] * att_w[p*NHID + c];
    float satt = sigf(s);

    int hs = (p < 4) ? 0 : 1;
    const float* dw = (p < 4) ? du_w : dl_w;
    float d = (p < 4) ? du_b[0] : dl_b[0];
    #pragma unroll
    for (int c = 0; c < NHID; c++)
        d += xh[((size_t)(hs*BB + b)*NHID + c)*HWD + px] * dw[c];
    float dec = sigf(d);

    float xpp = 0.f;
    for (int e = 0; e < NE; e++) {
        if (edst[e] != p) continue;
        float sab = o_b[e];
        #pragma unroll
        for (int c = 0; c < NHID; c++) {
            float v = t2all[((size_t)(e*BB + b)*NHID + c)*HWD + px];
            v = fmaxf(fmaf(v, s2[e*NHID+c], sh2[e*NHID+c]), 0.f);
            sab += v * o_w[e*NHID + c];
        }
        int sp = esrc[e];
        float sa = a_b[e];
        #pragma unroll
        for (int c = 0; c < NHID; c++)
            sa += xp[((size_t)(sp*BB + b)*NHID + c)*HWD + px] * a_w[e*NHID + c];
        xpp += sigf(sab) * (1.f - sigf(sa));
    }
    float gate = 1.f + dec + satt + xpp;

    const float* wq = wq_all + (size_t)p*NIN*NHID;
    const float* pf = p_fea + (size_t)b*NIN*HWD + px;
    float acc[NHID];
    #pragma unroll
    for (int o = 0; o < NHID; o++) acc[o] = 0.f;
    for (int c = 0; c < NIN; c += 8) {
        float v0 = pf[(size_t)(c+0)*HWD];
        float v1 = pf[(size_t)(c+1)*HWD];
        float v2 = pf[(size_t)(c+2)*HWD];
        float v3 = pf[(size_t)(c+3)*HWD];
        float v4 = pf[(size_t)(c+4)*HWD];
        float v5 = pf[(size_t)(c+5)*HWD];
        float v6 = pf[(size_t)(c+6)*HWD];
        float v7 = pf[(size_t)(c+7)*HWD];
        const float* wc = wq + c*NHID;
        #pragma unroll
        for (int o = 0; o < NHID; o++) acc[o] = fmaf(v0, wc[o], acc[o]);
        #pragma unroll
        for (int o = 0; o < NHID; o++) acc[o] = fmaf(v1, wc[NHID + o], acc[o]);
        #pragma unroll
        for (int o = 0; o < NHID; o++) acc[o] = fmaf(v2, wc[2*NHID + o], acc[o]);
        #pragma unroll
        for (int o = 0; o < NHID; o++) acc[o] = fmaf(v3, wc[3*NHID + o], acc[o]);
        #pragma unroll
        for (int o = 0; o < NHID; o++) acc[o] = fmaf(v4, wc[4*NHID + o], acc[o]);
        #pragma unroll
        for (int o = 0; o < NHID; o++) acc[o] = fmaf(v5, wc[5*NHID + o], acc[o]);
        #pragma unroll
        for (int o = 0; o < NHID; o++) acc[o] = fmaf(v6, wc[6*NHID + o], acc[o]);
        #pragma unroll
        for (int o = 0; o < NHID; o++) acc[o] = fmaf(v7, wc[7*NHID + o], acc[o]);
    }
    float* yp = y + ((size_t)(p*BB + b)*NHID)*HWD + px;
    #pragma unroll
    for (int o = 0; o < NHID; o++) yp[(size_t)o*HWD] = acc[o] * gate;
}

// ---------------------------------------------------------------------------
// out = relu(bn5(y));   grid: (36, B*HID, P)
// ---------------------------------------------------------------------------
__global__ __launch_bounds__(256)
void out_kernel(const float* __restrict__ y, const float* __restrict__ s5,
                const float* __restrict__ t5, float* __restrict__ out)
{
    int px = blockIdx.x * 256 + threadIdx.x;
    int bo = blockIdx.y, p = blockIdx.z;
    int b = bo / NHID, o = bo % NHID;
    size_t idx = ((size_t)(p*BB + b)*NHID + o)*HWD + px;
    out[idx] = fmaxf(fmaf(y[idx], s5[p*NHID+o], t5[p*NHID+o]), 0.f);
}

// ---------------------------------------------------------------------------
// launcher
// ---------------------------------------------------------------------------
extern "C" void kernel_launch(void* const* d_in, const int* in_sizes, int n_in,
                              void* d_out, int out_size, void* d_ws, size_t ws_size,
                              hipStream_t stream)
{
    (void)in_sizes; (void)n_in; (void)out_size; (void)ws_size;

    const float* p_fea  = (const float*)d_in[0];
    const float* xp     = (const float*)d_in[1];
    const float* xh     = (const float*)d_in[2];
    const float* att_w  = (const float*)d_in[3];
    const float* att_b  = (const float*)d_in[4];
    const float* du_w   = (const float*)d_in[5];
    const float* du_b   = (const float*)d_in[6];
    const float* dl_w   = (const float*)d_in[7];
    const float* dl_b   = (const float*)d_in[8];
    const float* upd_w  = (const float*)d_in[9];
    const float* upd_g  = (const float*)d_in[10];
    const float* upd_b  = (const float*)d_in[11];
    const float* off1_w = (const float*)d_in[12];
    const float* off1_b = (const float*)d_in[13];
    const float* dcn1_w = (const float*)d_in[14];
    const float* bn1_g  = (const float*)d_in[15];
    const float* bn1_b  = (const float*)d_in[16];
    const float* off2_w = (const float*)d_in[17];
    const float* off2_b = (const float*)d_in[18];
    const float* dcn2_w = (const float*)d_in[19];
    const float* bn2_g  = (const float*)d_in[20];
    const float* bn2_b  = (const float*)d_in[21];
    const float* out_w  = (const float*)d_in[22];
    const float* out_b  = (const float*)d_in[23];
    const float* aatt_w = (const float*)d_in[24];
    const float* aatt_b = (const float*)d_in[25];
    const int* esrc     = (const int*)d_in[26];
    const int* edst     = (const int*)d_in[27];
    float* outp = (float*)d_out;
    float* ws = (float*)d_ws;

    // workspace layout (float offsets; ushort arrays occupy half-floats)
    constexpr size_t o_x1   = 0;                                    // [E][B][20][HWD]
    constexpr size_t o_t2   = o_x1  + (size_t)NE*BB*CIN2*HWD;       // [E][B][10][HWD]
    constexpr size_t o_bf1  = o_t2  + (size_t)NE*BB*NHID*HWD;       // 110592 ush
    constexpr size_t o_b1   = o_bf1 + 55296;
    constexpr size_t o_ws1  = o_b1  + 324;                          // 110592 ush
    constexpr size_t o_bf2  = o_ws1 + 55296;                        // 110592 ush
    constexpr size_t o_b2   = o_bf2 + 55296;
    constexpr size_t o_ws2  = o_b2  + 324;                          // 55296 ush
    constexpr size_t o_uw   = o_ws2 + 27648;
    constexpr size_t o_bn1s = o_uw  + 15360;
    constexpr size_t o_bn1t = o_bn1s + NE*CIN2;
    constexpr size_t o_bn2s = o_bn1t + NE*CIN2;
    constexpr size_t o_bn2t = o_bn2s + NE*NHID;
    constexpr size_t o_bn5s = o_bn2t + NE*NHID;
    constexpr size_t o_bn5t = o_bn5s + NPART*NHID;
    constexpr size_t o_y    = o_bn5t + NPART*NHID;                  // [P][B][10][HWD]
    float* x1 = ws + o_x1;
    float* t2 = ws + o_t2;
    float* y  = ws + o_y;
    unsigned short* bf1 = (unsigned short*)(ws + o_bf1);
    unsigned short* ws1 = (unsigned short*)(ws + o_ws1);
    unsigned short* bf2 = (unsigned short*)(ws + o_bf2);
    unsigned short* ws2 = (unsigned short*)(ws + o_ws2);

    // items: 110592+324+110592+110592+324+55296+15360 = 403080 -> 1575 blocks
    xpose_weights<<<dim3(1575), 256, 0, stream>>>(
        off1_w, off1_b, dcn1_w, off2_w, off2_b, dcn2_w, upd_w,
        bf1, ws+o_b1, ws1, bf2, ws+o_b2, ws2, ws+o_uw);

    dcn_tiled<CIN2, true><<<dim3(36, BB, NE), 256, 0, stream>>>(
        nullptr, xp, esrc, edst, bf1, ws+o_b1, ws1,
        nullptr, nullptr, x1);

    bn_stats_flat<CIN2><<<dim3(NE*CIN2), 256, 0, stream>>>(
        x1, bn1_g, bn1_b, ws+o_bn1s, ws+o_bn1t);

    dcn_tiled<NHID, false><<<dim3(36, BB, NE), 256, 0, stream>>>(
        x1, nullptr, esrc, edst, bf2, ws+o_b2, ws2,
        ws+o_bn1s, ws+o_bn1t, t2);

    bn_stats_flat<NHID><<<dim3(NE*NHID), 256, 0, stream>>>(
        t2, bn2_g, bn2_b, ws+o_bn2s, ws+o_bn2t);

    mgq_kernel<<<dim3(36, BB, NPART), 256, 0, stream>>>(
        t2, ws+o_bn2s, ws+o_bn2t, out_w, out_b, aatt_w, aatt_b, xp, xh,
        att_w, att_b, du_w, du_b, dl_w, dl_b, esrc, edst,
        p_fea, ws+o_uw, y);

    bn_stats_flat<NHID><<<dim3(NPART*NHID), 256, 0, stream>>>(
        y, upd_g, upd_b, ws+o_bn5s, ws+o_bn5t);

    out_kernel<<<dim3(36, BB*NHID, NPART), 256, 0, stream>>>(
        y, ws+o_bn5s, ws+o_bn5t, outp);
}